// Round 7
// baseline (4057.381 us; speedup 1.0000x reference)
//
#include <hip/hip_runtime.h>
#include <cstdint>
#include <cstddef>

#define NTR 16384
#define NQR 4096
#define NROW 20480
#define DF  128
#define NCL 19

typedef unsigned short u16;
typedef __attribute__((ext_vector_type(8))) short bf16x8;
typedef __attribute__((ext_vector_type(4))) float f32x4;

// ---- workspace layout (bytes) ----
#define OFF_RN    (size_t)0                  // float[20480]
#define OFF_EXT   (size_t)81920              // u16[20480][256] (hi|lo bf16)
#define OFF_FSN   (size_t)10567680           // int[20480][4][24]
#define OFF_NBRT  (size_t)18432000           // int[16384][20]
#define OFF_NBRQ  (size_t)19742720           // int[4096][20]
#define OFF_HIST  (size_t)20070400           // int[2][2][19][32]
#define OFF_COND  (size_t)20080128           // float[2][2][19][32]
#define OFF_PRIOR (size_t)20089856           // float[19]
#define WS_NEEDED (size_t)20089936

// separately-rounded multiply (asm barrier blocks mul+add -> fma contraction)
__device__ __forceinline__ float mulr(float a, float b) {
  float m = a * b;
  asm volatile("" : "+v"(m));
  return m;
}

// bf16 round-to-nearest-even of an f32 (manual, deterministic, finite inputs)
__device__ __forceinline__ u16 bf16_rne(float x) {
  union { float f; unsigned u; } v; v.f = x;
  unsigned r = (v.u + 0x7fffu + ((v.u >> 16) & 1u)) >> 16;
  return (u16)r;
}
__device__ __forceinline__ float bf16_f32(u16 h) {
  union { unsigned u; float f; } v; v.u = ((unsigned)h) << 16;
  return v.f;
}

// ---------------- hi/lo bf16 split of all rows ----------------
__global__ __launch_bounds__(256) void ext_kernel(const float* __restrict__ train,
                                                  const float* __restrict__ feat,
                                                  u16* __restrict__ ext) {
  int gid = blockIdx.x * 256 + threadIdx.x;  // 2560 blocks -> 655360 (x4 elems)
  int idx4 = gid << 2;
  int row = idx4 >> 7, k = idx4 & 127;
  const float* src = (row < NTR) ? (train + (size_t)row * DF) : (feat + (size_t)(row - NTR) * DF);
  float4 v = *reinterpret_cast<const float4*>(src + k);
  const float xs[4] = {v.x, v.y, v.z, v.w};
  u16 hi[4], lo[4];
#pragma unroll
  for (int j = 0; j < 4; ++j) {
    hi[j] = bf16_rne(xs[j]);
    lo[j] = bf16_rne(xs[j] - bf16_f32(hi[j]));
  }
  *reinterpret_cast<ushort4*>(ext + (size_t)row * 256 + k) = make_ushort4(hi[0], hi[1], hi[2], hi[3]);
  *reinterpret_cast<ushort4*>(ext + (size_t)row * 256 + 128 + k) = make_ushort4(lo[0], lo[1], lo[2], lo[3]);
}

// ---------------- row norms: exact reference realization (no FMA) ------------
__global__ __launch_bounds__(256) void norms_kernel(const float* __restrict__ train,
                                                    const float* __restrict__ feat,
                                                    float* __restrict__ rn) {
  int i = blockIdx.x * 256 + threadIdx.x;  // 80 blocks -> 20480
  const float* src = (i < NTR) ? (train + (size_t)i * DF) : (feat + (size_t)(i - NTR) * DF);
  float s = 0.0f;
  for (int k = 0; k < DF; ++k) {
    float x = src[k];
    s = s + mulr(x, x);
  }
  rn[i] = s;
}

// ---------------- sorted top-24 insertion (registers only, fully static) -----
__device__ __forceinline__ void insert24(float (&sd)[24], int (&si)[24], float d, int idx) {
#pragma unroll
  for (int j = 23; j >= 1; --j) {
    bool w = sd[j] > d;
    bool c = sd[j - 1] > d;
    if (w) {
      sd[j] = c ? sd[j - 1] : d;
      si[j] = c ? si[j - 1] : idx;
    }
  }
  if (sd[0] > d) { sd[0] = d; si[0] = idx; }
}

// ---------------- FILTER: split-bf16 MFMA distance GEMM + top-24/slice -------
// Block: 256 thr (4 waves, 2x2). Tile: 128 rows x 128 cands per n-step.
// K=384 bf16 = 3 passes of 128 over ext: A chunks (h,h,l), B chunks (h,l,h).
// score = nb - 2*dot (row-constant na dropped). Selection identical semantics
// to the verified scaffolding; exact no-FMA rescore downstream.
__global__ __launch_bounds__(256, 1) void filter_kernel(const u16* __restrict__ ext,
                                                        const float* __restrict__ rn,
                                                        int* __restrict__ fsn) {
  __shared__ __align__(16) char smem[54272];
  u16 (*As)[40] = reinterpret_cast<u16 (*)[40]>(smem);            // 10240 B
  u16 (*Bs)[40] = reinterpret_cast<u16 (*)[40]>(smem + 10240);    // 10240 B
  float (*Dt)[132] = reinterpret_cast<float (*)[132]>(smem + 20480);  // [64 cols][132 rows] 33792 B

  const int bid = blockIdx.x;               // 640 blocks
  const int lid = (bid & 7) * 80 + (bid >> 3);   // XCD-chunked, slice-major
  const int slice = lid / 160, rowblk = lid % 160;
  const int grow0 = rowblk * 128, cbase0 = slice * 4096;

  const int tid = threadIdx.x;
  const int wave = tid >> 6, lane = tid & 63;
  const int wm = wave >> 1, wn = wave & 1;
  const int l15 = lane & 15, l4 = lane >> 4;
  const int selrow = tid & 127, selseg = tid >> 7;

  float sd[24];
  int si[24];
#pragma unroll
  for (int t = 0; t < 24; ++t) { sd[t] = 3.0e38f; si[t] = 0x7fffffff; }

  for (int nt0 = 0; nt0 < 4096; nt0 += 128) {
    f32x4 acc[4][4];
#pragma unroll
    for (int i = 0; i < 4; ++i)
#pragma unroll
      for (int j = 0; j < 4; ++j) acc[i][j] = (f32x4){0.f, 0.f, 0.f, 0.f};

#pragma unroll 1
    for (int t = 0; t < 12; ++t) {
      int p = t >> 2, kk = (t & 3) * 32;
      int ao = (p == 2) ? 128 : 0;
      int bo = (p == 1) ? 128 : 0;
      __syncthreads();
      // stage A[128][32] and B[128][32] bf16 (8192 B each: 512 float4 writes)
      for (int u = tid; u < 512; u += 256) {
        int r = u >> 2, q = (u & 3) << 3;  // row, u16-column (0,8,16,24)
        *reinterpret_cast<float4*>(&As[r][q]) =
            *reinterpret_cast<const float4*>(ext + (size_t)(grow0 + r) * 256 + ao + kk + q);
        *reinterpret_cast<float4*>(&Bs[r][q]) =
            *reinterpret_cast<const float4*>(ext + (size_t)(cbase0 + nt0 + r) * 256 + bo + kk + q);
      }
      __syncthreads();
      bf16x8 af[4], bf[4];
#pragma unroll
      for (int fm = 0; fm < 4; ++fm)
        af[fm] = *reinterpret_cast<const bf16x8*>(&As[wm * 64 + fm * 16 + l15][l4 * 8]);
#pragma unroll
      for (int fn = 0; fn < 4; ++fn)
        bf[fn] = *reinterpret_cast<const bf16x8*>(&Bs[wn * 64 + fn * 16 + l15][l4 * 8]);
#pragma unroll
      for (int fm = 0; fm < 4; ++fm)
#pragma unroll
        for (int fn = 0; fn < 4; ++fn)
          acc[fm][fn] = __builtin_amdgcn_mfma_f32_16x16x32_bf16(af[fm], bf[fn], acc[fm][fn], 0, 0, 0);
    }

    // epilogue + selection in two 64-cand halves (col-major Dt, 2-way banks)
#pragma unroll 1
    for (int h = 0; h < 2; ++h) {
      __syncthreads();
      if (wn == h) {
        float rnv[4];
#pragma unroll
        for (int fn = 0; fn < 4; ++fn)
          rnv[fn] = rn[cbase0 + nt0 + h * 64 + fn * 16 + l15];
#pragma unroll
        for (int fm = 0; fm < 4; ++fm)
#pragma unroll
          for (int fn = 0; fn < 4; ++fn) {
            int c = fn * 16 + l15;
            int r0 = wm * 64 + fm * 16 + l4 * 4;
            f32x4 v;
#pragma unroll
            for (int j = 0; j < 4; ++j) v[j] = rnv[fn] - 2.0f * acc[fm][fn][j];
            *reinterpret_cast<f32x4*>(&Dt[c][r0]) = v;
          }
      }
      __syncthreads();
      int cb = selseg * 32;
#pragma unroll 1
      for (int c = cb; c < cb + 32; ++c) {
        float d = Dt[c][selrow];
        if (d < sd[23]) insert24(sd, si, d, cbase0 + nt0 + h * 64 + c);
      }
    }
  }

  // slice-end: merge the 2 segment lists per row -> fsn[row][slice][24]
  __syncthreads();
  float* md = reinterpret_cast<float*>(smem);
  int* mi = reinterpret_cast<int*>(smem + 24576);
  {
    int b = tid * 24;
#pragma unroll
    for (int t = 0; t < 24; ++t) { md[b + t] = sd[t]; mi[b + t] = si[t]; }
  }
  __syncthreads();
  if (tid < 128) {
    const float* LA = md + (size_t)tid * 24;        const int* IA = mi + (size_t)tid * 24;
    const float* LB = md + (size_t)(tid + 128) * 24; const int* IB = mi + (size_t)(tid + 128) * 24;
    int pa = 0, pb = 0;
    size_t ob = (size_t)(grow0 + tid) * 96 + (size_t)slice * 24;
    for (int t = 0; t < 24; ++t) {
      float da = LA[pa], db = LB[pb];
      int ja = IA[pa], jb = IB[pb];
      bool ca = da < db || (da == db && ja < jb);
      fsn[ob + t] = ca ? ja : jb;
      pa += ca; pb += !ca;
    }
  }
}

// ---------------- RESCORE: exact no-FMA chain on 96 cands/row, rank-select ---
__global__ __launch_bounds__(256) void rescore_kernel(const float* __restrict__ train,
                                                      const float* __restrict__ feat,
                                                      const float* __restrict__ rn,
                                                      const int* __restrict__ fsn,
                                                      int* __restrict__ nbrt,
                                                      int* __restrict__ nbrq) {
  __shared__ float rowf[2][DF];
  __shared__ float sc[2][96];
  __shared__ int sidx[2][96];
  const int sub = threadIdx.x >> 7;       // 2 rows per block
  const int t = threadIdx.x & 127;
  const int row = blockIdx.x * 2 + sub;   // 10240 blocks -> 20480
  const float* src = (row < NTR) ? (train + (size_t)row * DF) : (feat + (size_t)(row - NTR) * DF);
  rowf[sub][t] = src[t];
  __syncthreads();
  if (t < 96) {
    int ci = fsn[(size_t)row * 96 + t];
    ci = (ci < 0) ? 0 : ((ci >= NTR) ? (NTR - 1) : ci);  // defensive clamp (bug -> absmax, not fault)
    const float* tv = train + (size_t)ci * DF;
    float s = 0.0f;
    for (int k = 0; k < DF; ++k) s = s + mulr(rowf[sub][k], tv[k]);  // exact chain
    float t1 = rn[row] + rn[ci];
    sc[sub][t] = t1 - 2.0f * s;
    sidx[sub][t] = ci;
  }
  __syncthreads();
  if (t < 96) {
    float dm = sc[sub][t];
    int im = sidx[sub][t];
    int rank = 0;
    for (int i = 0; i < 96; ++i) {
      float di = sc[sub][i];
      int ii = sidx[sub][i];
      rank += (di < dm || (di == dm && ii < im));
    }
    if (rank < 20) {
      int* outp = (row < NTR) ? (nbrt + (size_t)row * 20) : (nbrq + (size_t)(row - NTR) * 20);
      outp[rank] = im;
    }
  }
}

// ---------------- label-count histograms (k=10 and k=20) ----------------
__global__ __launch_bounds__(256) void hist_kernel(const int* __restrict__ labels,
                                                   const int* __restrict__ nbrt,
                                                   int* __restrict__ ghist) {
  __shared__ int h[2432];
  int tid = threadIdx.x;
  for (int i = tid; i < 2432; i += 256) h[i] = 0;
  __syncthreads();
  int row = blockIdx.x * 256 + tid;  // 64 blocks -> 16384
  int nb[20];
#pragma unroll
  for (int j = 0; j < 20; ++j) nb[j] = nbrt[(size_t)row * 20 + j];
  int cnt[NCL];
#pragma unroll
  for (int c = 0; c < NCL; ++c) cnt[c] = 0;
#pragma unroll
  for (int j = 0; j < 10; ++j) {
    const int* lr = labels + (size_t)nb[j] * NCL;
#pragma unroll
    for (int c = 0; c < NCL; ++c) cnt[c] += lr[c];
  }
  const int* myl = labels + (size_t)row * NCL;
  int my[NCL];
#pragma unroll
  for (int c = 0; c < NCL; ++c) my[c] = myl[c];
#pragma unroll
  for (int c = 0; c < NCL; ++c)
    atomicAdd(&h[((0 * 2 + my[c]) * NCL + c) * 32 + cnt[c]], 1);
#pragma unroll
  for (int j = 10; j < 20; ++j) {
    const int* lr = labels + (size_t)nb[j] * NCL;
#pragma unroll
    for (int c = 0; c < NCL; ++c) cnt[c] += lr[c];
  }
#pragma unroll
  for (int c = 0; c < NCL; ++c)
    atomicAdd(&h[((1 * 2 + my[c]) * NCL + c) * 32 + cnt[c]], 1);
  __syncthreads();
  for (int i = tid; i < 2432; i += 256) {
    int v = h[i];
    if (v) atomicAdd(&ghist[i], v);
  }
}

// ---------------- conditional tables + priors ----------------
__global__ __launch_bounds__(256) void prep_kernel(const int* __restrict__ ghist,
                                                   float* __restrict__ cond,
                                                   float* __restrict__ prior) {
  __shared__ int cpos[NCL];
  int tid = threadIdx.x;
  if (tid < NCL) {
    int s = 0;
    for (int d = 0; d < 32; ++d) s += ghist[((0 * 2 + 1) * NCL + tid) * 32 + d];
    cpos[tid] = s;
    prior[tid] = (1.0f + (float)s) / (2.0f + (float)NTR);
  }
  __syncthreads();
  for (int i = tid; i < 2432; i += 256) {
    int cc = (i >> 5) % NCL;
    int pos = ((i >> 5) / NCL) & 1;
    int ki = i / (2 * NCL * 32);
    int k = ki ? 20 : 10;
    float num = 1.0f + (float)ghist[i];
    float den = (float)(k + 1) + (float)(pos ? cpos[cc] : (NTR - cpos[cc]));
    cond[i] = num / den;
  }
}

// ---------------- posterior output ----------------
__global__ __launch_bounds__(256) void out_kernel(const int* __restrict__ labels,
                                                  const int* __restrict__ nbrq,
                                                  const float* __restrict__ cond,
                                                  const float* __restrict__ prior,
                                                  float* __restrict__ out) {
  int q = blockIdx.x * 256 + threadIdx.x;  // 16 blocks -> 4096
  int nb[20];
#pragma unroll
  for (int j = 0; j < 20; ++j) nb[j] = nbrq[(size_t)q * 20 + j];
  int cnt[NCL], d10[NCL];
#pragma unroll
  for (int c = 0; c < NCL; ++c) cnt[c] = 0;
#pragma unroll
  for (int j = 0; j < 10; ++j) {
    const int* lr = labels + (size_t)nb[j] * NCL;
#pragma unroll
    for (int c = 0; c < NCL; ++c) cnt[c] += lr[c];
  }
#pragma unroll
  for (int c = 0; c < NCL; ++c) d10[c] = cnt[c];
#pragma unroll
  for (int j = 10; j < 20; ++j) {
    const int* lr = labels + (size_t)nb[j] * NCL;
#pragma unroll
    for (int c = 0; c < NCL; ++c) cnt[c] += lr[c];
  }
#pragma unroll
  for (int ki = 0; ki < 2; ++ki) {
#pragma unroll
    for (int c = 0; c < NCL; ++c) {
      int delta = ki ? cnt[c] : d10[c];
      float pr = prior[c];
      float pt = pr * cond[((ki * 2 + 1) * NCL + c) * 32 + delta];
      float pf = (1.0f - pr) * cond[((ki * 2 + 0) * NCL + c) * 32 + delta];
      out[((size_t)ki * NQR + q) * NCL + c] = pt / (pt + pf);
    }
  }
}

extern "C" void kernel_launch(void* const* d_in, const int* in_sizes, int n_in,
                              void* d_out, int out_size, void* d_ws, size_t ws_size,
                              hipStream_t stream) {
  const float* feat = (const float*)d_in[0];     // [4096,128]
  const float* train = (const float*)d_in[1];    // [16384,128]
  const int* labels = (const int*)d_in[2];       // [16384,19]
  float* out = (float*)d_out;                    // [2,4096,19]
  if (ws_size < WS_NEEDED) return;               // loud failure via poisoned output
  char* w = (char*)d_ws;
  float* rn = (float*)(w + OFF_RN);
  u16* ext = (u16*)(w + OFF_EXT);
  int* fsn = (int*)(w + OFF_FSN);
  int* nbrt = (int*)(w + OFF_NBRT);
  int* nbrq = (int*)(w + OFF_NBRQ);
  int* ghist = (int*)(w + OFF_HIST);
  float* cond = (float*)(w + OFF_COND);
  float* prior = (float*)(w + OFF_PRIOR);

  hipMemsetAsync(ghist, 0, 2432 * 4, stream);
  ext_kernel<<<2560, 256, 0, stream>>>(train, feat, ext);
  norms_kernel<<<80, 256, 0, stream>>>(train, feat, rn);
  filter_kernel<<<640, 256, 0, stream>>>(ext, rn, fsn);
  rescore_kernel<<<10240, 256, 0, stream>>>(train, feat, rn, fsn, nbrt, nbrq);
  hist_kernel<<<64, 256, 0, stream>>>(labels, nbrt, ghist);
  prep_kernel<<<1, 256, 0, stream>>>(ghist, cond, prior);
  out_kernel<<<16, 256, 0, stream>>>(labels, nbrq, cond, prior, out);
}

// Round 8
// 2596.816 us; speedup vs baseline: 1.5624x; 1.5624x over previous
//
#include <hip/hip_runtime.h>
#include <cstdint>
#include <cstddef>

#define NTR 16384
#define NQR 4096
#define NROW 20480
#define DF  128
#define NCL 19

typedef unsigned short u16;
typedef unsigned int u32;
typedef __attribute__((ext_vector_type(8))) short bf16x8;
typedef __attribute__((ext_vector_type(16))) float f32x16;

// ---- workspace layout (bytes) ----
#define OFF_RN    (size_t)0                  // float[20480]
#define OFF_QEXT  (size_t)81920              // u16[20480][144]
#define OFF_CEXT  (size_t)5980160            // u16[16384][144] (negated + hb dims)
#define OFF_FSN   (size_t)10698752           // u16[20480][192]
#define OFF_NBRT  (size_t)18563072           // int[16384][20]
#define OFF_NBRQ  (size_t)19873792           // int[4096][20]
#define OFF_HIST  (size_t)20201472           // int[2][2][19][32]
#define OFF_COND  (size_t)20211200           // float[2][2][19][32]
#define OFF_PRIOR (size_t)20220928           // float[19]
#define WS_NEEDED (size_t)20221008

// separately-rounded multiply (asm barrier blocks mul+add -> fma contraction)
__device__ __forceinline__ float mulr(float a, float b) {
  float m = a * b;
  asm volatile("" : "+v"(m));
  return m;
}

__device__ __forceinline__ u16 bf16_rne(float x) {
  union { float f; unsigned u; } v; v.f = x;
  unsigned r = (v.u + 0x7fffu + ((v.u >> 16) & 1u)) >> 16;
  return (u16)r;
}
__device__ __forceinline__ float bf16_f32(u16 h) {
  union { unsigned u; float f; } v; v.u = ((unsigned)h) << 16;
  return v.f;
}

__device__ __forceinline__ void gload_lds16(const void* g, void* lds) {
  __builtin_amdgcn_global_load_lds(
      (const __attribute__((address_space(1))) unsigned int*)g,
      (__attribute__((address_space(3))) unsigned int*)lds, 16, 0, 0);
}

// ---------------- row norms: exact reference realization (no FMA) ------------
__global__ __launch_bounds__(256) void norms_kernel(const float* __restrict__ train,
                                                    const float* __restrict__ feat,
                                                    float* __restrict__ rn) {
  int i = blockIdx.x * 256 + threadIdx.x;  // 80 blocks -> 20480
  const float* src = (i < NTR) ? (train + (size_t)i * DF) : (feat + (size_t)(i - NTR) * DF);
  float s = 0.0f;
  for (int k = 0; k < DF; ++k) {
    float x = src[k];
    s = s + mulr(x, x);
  }
  rn[i] = s;
}

// ---------------- ext: bf16 rows + metric K-extension ----------------
// qext[row][144]: [bf16(x_k)]*128, dim128=1.0, dim129=1.0, rest 0
// cext[c][144]:   [bf16(-x_k)]*128, dim128=hb_hi, dim129=hb_lo, rest 0
// where hb = 0.5*rn[c] + 256  ->  mfma(C,Q) = 256 + hb - dot  (positive metric)
__global__ __launch_bounds__(256) void ext_kernel(const float* __restrict__ train,
                                                  const float* __restrict__ feat,
                                                  const float* __restrict__ rn,
                                                  u16* __restrict__ qext,
                                                  u16* __restrict__ cext) {
  int row = blockIdx.x * 2 + (threadIdx.x >> 7);  // 10240 blocks -> 20480
  int k = threadIdx.x & 127;
  const float* srcp = (row < NTR) ? (train + (size_t)row * DF) : (feat + (size_t)(row - NTR) * DF);
  float x = srcp[k];
  u16 b = bf16_rne(x);
  qext[(size_t)row * 144 + k] = b;
  if (row < NTR) cext[(size_t)row * 144 + k] = (u16)(b ^ 0x8000u);
  if (k < 16) {
    qext[(size_t)row * 144 + 128 + k] = (k < 2) ? (u16)0x3F80 : (u16)0;
    if (row < NTR) {
      float hbf = 0.5f * rn[row] + 256.0f;
      u16 hi = bf16_rne(hbf);
      u16 lo = bf16_rne(hbf - bf16_f32(hi));
      cext[(size_t)row * 144 + 128 + k] = (k == 0) ? hi : ((k == 1) ? lo : (u16)0);
    }
  }
}

// ---------------- sorted top-16 insertion on packed u32 keys ----------------
__device__ __forceinline__ void insert16(u32 (&sd)[16], u32 key) {
#pragma unroll
  for (int j = 15; j >= 1; --j) {
    bool w = sd[j] > key;
    bool c = sd[j - 1] > key;
    if (w) sd[j] = c ? sd[j - 1] : key;
  }
  if (sd[0] > key) sd[0] = key;
}

// ---------------- FILTER: swapped 32x32x16 MFMA, q-in-regs, dbuf LDS ---------
// Grid 1280: slice = bid&7 (XCD-affine, 2048 cands L2-resident), rowblk = bid>>3.
// Block 256 thr = 4 waves (2 q-halves x 2 c-halves); wave = 64 q x 32 c.
// acc = mfma(cand_tile, query_tile): lane owns query col (l&31), 16 cand rows.
// Per n-tile(64c): 9 ds_read_b128 + 18 mfma + epilogue cmp/insert + 1 barrier.
__global__ __launch_bounds__(256, 2) void filter_kernel(const u16* __restrict__ qext,
                                                        const u16* __restrict__ cext,
                                                        u16* __restrict__ fsn) {
  __shared__ __align__(16) char smem[36864];  // cbuf[2]:16KB, hbuf[2]:2KB
  const int bid = blockIdx.x;
  const int slice = bid & 7, rowblk = bid >> 3;
  const int grow0 = rowblk * 128;
  const int cslice0 = slice * 2048;
  const int tid = threadIdx.x;
  const int wave = tid >> 6, lane = tid & 63;
  const int wq = wave >> 1, wc = wave & 1;
  const int l31 = lane & 31, h = lane >> 5;
  const char* qb = (const char*)qext;
  const char* cbg = (const char*)cext;

  // q fragments in registers: 2 q-tiles x 9 ksteps
  bf16x8 qf0[9], qf1[9];
  const int q0 = grow0 + wq * 64;
#pragma unroll
  for (int ks = 0; ks < 8; ++ks) {
    qf0[ks] = *(const bf16x8*)(qb + (size_t)(q0 + l31) * 288 + ks * 32 + h * 16);
    qf1[ks] = *(const bf16x8*)(qb + (size_t)(q0 + 32 + l31) * 288 + ks * 32 + h * 16);
  }
  qf0[8] = *(const bf16x8*)(qb + (size_t)(q0 + l31) * 288 + 256 + h * 16);
  qf1[8] = *(const bf16x8*)(qb + (size_t)(q0 + 32 + l31) * 288 + 256 + h * 16);

  u32 sd0[16], sd1[16];
#pragma unroll
  for (int t = 0; t < 16; ++t) { sd0[t] = 0x7F7FFFFFu; sd1[t] = 0x7F7FFFFFu; }

  // async stage of cand tile nt into buffer buf (source pre-swizzled, LDS linear)
  auto STAGE = [&](int buf, int nt) {
    const size_t c0 = (size_t)cslice0 + (size_t)nt * 64;
    char* cb = smem + buf * 16384;
    char* hb = smem + 32768 + buf * 2048;
#pragma unroll
    for (int j = 0; j < 4; ++j) {
      int I = wave + 4 * j;          // 0..15
      int G = I * 64 + lane;
      int r = G >> 4, g = G & 15;
      const char* src = cbg + (c0 + r) * 288 + ((g << 4) ^ ((r & 7) << 4));
      gload_lds16(src, cb + I * 1024);
    }
    if (wave < 2) {                  // 2 issues for hb dims (32B/row)
      int GG = wave * 64 + lane;
      int r = GG >> 1, half = GG & 1;
      const char* src = cbg + (c0 + r) * 288 + 256 + half * 16;
      gload_lds16(src, hb + wave * 1024);
    }
  };

  STAGE(0, 0);
  __syncthreads();

  const int crow = wc * 32 + l31;
  for (int nt = 0; nt < 32; ++nt) {
    const int cur = nt & 1;
    if (nt < 31) STAGE(cur ^ 1, nt + 1);

    const char* cbp = smem + cur * 16384 + crow * 256;
    const char* hbp = smem + 32768 + cur * 2048 + crow * 32 + h * 16;
    f32x16 acc0 = {0.f,0.f,0.f,0.f,0.f,0.f,0.f,0.f,0.f,0.f,0.f,0.f,0.f,0.f,0.f,0.f};
    f32x16 acc1 = {0.f,0.f,0.f,0.f,0.f,0.f,0.f,0.f,0.f,0.f,0.f,0.f,0.f,0.f,0.f,0.f};
#pragma unroll
    for (int ks = 0; ks < 8; ++ks) {
      bf16x8 cf = *(const bf16x8*)(cbp + ((ks * 32 + h * 16) ^ ((crow & 7) << 4)));
      acc0 = __builtin_amdgcn_mfma_f32_32x32x16_bf16(cf, qf0[ks], acc0, 0, 0, 0);
      acc1 = __builtin_amdgcn_mfma_f32_32x32x16_bf16(cf, qf1[ks], acc1, 0, 0, 0);
    }
    {
      bf16x8 cf = *(const bf16x8*)hbp;
      acc0 = __builtin_amdgcn_mfma_f32_32x32x16_bf16(cf, qf0[8], acc0, 0, 0, 0);
      acc1 = __builtin_amdgcn_mfma_f32_32x32x16_bf16(cf, qf1[8], acc1, 0, 0, 0);
    }

    // selection: key = (f32bits & ~0xFFF) | slice-local idx  (metric > 0)
    const int cb_idx = nt * 64 + wc * 32 + 4 * h;
    float th0 = __uint_as_float(sd0[15]);
    float th1 = __uint_as_float(sd1[15]);
#pragma unroll
    for (int j = 0; j < 16; ++j) {
      const int cl = cb_idx + (j & 3) + 8 * (j >> 2);
      float s0 = acc0[j];
      if (s0 < th0) {
        u32 key = (__float_as_uint(s0) & 0xFFFFF000u) | (u32)cl;
        insert16(sd0, key);
        th0 = __uint_as_float(sd0[15]);
      }
      float s1 = acc1[j];
      if (s1 < th1) {
        u32 key = (__float_as_uint(s1) & 0xFFFFF000u) | (u32)cl;
        insert16(sd1, key);
        th1 = __uint_as_float(sd1[15]);
      }
    }
    __syncthreads();  // staged next buf ready; reads of cur complete
  }

  // dump per-thread lists, then 4-way merge per row -> fsn[row][slice*24..+24]
  u32* md = (u32*)smem;
  {
    int b = tid * 32;
#pragma unroll
    for (int t = 0; t < 16; ++t) { md[b + t] = sd0[t]; md[b + 16 + t] = sd1[t]; }
  }
  __syncthreads();
  if (tid < 128) {
    const int r = tid;
    const int rwq = r >> 6, rqt = (r >> 5) & 1, rl = r & 31;
    const u32* L[4];
#pragma unroll
    for (int wcc = 0; wcc < 2; ++wcc)
#pragma unroll
      for (int hh = 0; hh < 2; ++hh)
        L[wcc * 2 + hh] = md + (size_t)(((rwq * 2 + wcc) * 64) + hh * 32 + rl) * 32 + rqt * 16;
    int p0 = 0, p1 = 0, p2 = 0, p3 = 0;
    size_t ob = (size_t)(grow0 + r) * 192 + (size_t)slice * 24;
    for (int t = 0; t < 24; ++t) {
      u32 k0 = (p0 < 16) ? L[0][p0] : 0xFFFFFFFFu;
      u32 k1 = (p1 < 16) ? L[1][p1] : 0xFFFFFFFFu;
      u32 k2 = (p2 < 16) ? L[2][p2] : 0xFFFFFFFFu;
      u32 k3 = (p3 < 16) ? L[3][p3] : 0xFFFFFFFFu;
      bool a01 = k0 <= k1; u32 kA = a01 ? k0 : k1;
      bool a23 = k2 <= k3; u32 kB = a23 ? k2 : k3;
      bool ab = kA <= kB;  u32 km = ab ? kA : kB;
      fsn[ob + t] = (u16)(cslice0 + (km & 0xFFFu));
      int win = ab ? (a01 ? 0 : 1) : (a23 ? 2 : 3);
      p0 += (win == 0); p1 += (win == 1); p2 += (win == 2); p3 += (win == 3);
    }
  }
}

// ---------------- RESCORE: exact no-FMA chain on 192 cands/row, rank-select --
__global__ __launch_bounds__(192) void rescore_kernel(const float* __restrict__ train,
                                                      const float* __restrict__ feat,
                                                      const float* __restrict__ rn,
                                                      const u16* __restrict__ fsn,
                                                      int* __restrict__ nbrt,
                                                      int* __restrict__ nbrq) {
  __shared__ float rowf[DF];
  __shared__ float sc[192];
  __shared__ int sidx[192];
  const int row = blockIdx.x;  // 20480 blocks
  const int t = threadIdx.x;
  const float* src = (row < NTR) ? (train + (size_t)row * DF) : (feat + (size_t)(row - NTR) * DF);
  if (t < DF) rowf[t] = src[t];
  __syncthreads();
  {
    int ci = (int)fsn[(size_t)row * 192 + t];
    if (ci >= NTR) ci = NTR - 1;  // defensive (bug -> absmax, not fault)
    const float* tv = train + (size_t)ci * DF;
    float s = 0.0f;
    for (int k = 0; k < DF; ++k) s = s + mulr(rowf[k], tv[k]);  // exact chain
    float t1 = rn[row] + rn[ci];
    sc[t] = t1 - 2.0f * s;
    sidx[t] = ci;
  }
  __syncthreads();
  {
    float dm = sc[t];
    int im = sidx[t];
    int rank = 0;
    for (int i = 0; i < 192; ++i) {
      float di = sc[i];
      int ii = sidx[i];
      rank += (di < dm || (di == dm && ii < im));
    }
    if (rank < 20) {
      int* outp = (row < NTR) ? (nbrt + (size_t)row * 20) : (nbrq + (size_t)(row - NTR) * 20);
      outp[rank] = im;
    }
  }
}

// ---------------- label-count histograms (k=10 and k=20) ----------------
__global__ __launch_bounds__(256) void hist_kernel(const int* __restrict__ labels,
                                                   const int* __restrict__ nbrt,
                                                   int* __restrict__ ghist) {
  __shared__ int h[2432];
  int tid = threadIdx.x;
  for (int i = tid; i < 2432; i += 256) h[i] = 0;
  __syncthreads();
  int row = blockIdx.x * 256 + tid;  // 64 blocks -> 16384
  int nb[20];
#pragma unroll
  for (int j = 0; j < 20; ++j) nb[j] = nbrt[(size_t)row * 20 + j];
  int cnt[NCL];
#pragma unroll
  for (int c = 0; c < NCL; ++c) cnt[c] = 0;
#pragma unroll
  for (int j = 0; j < 10; ++j) {
    const int* lr = labels + (size_t)nb[j] * NCL;
#pragma unroll
    for (int c = 0; c < NCL; ++c) cnt[c] += lr[c];
  }
  const int* myl = labels + (size_t)row * NCL;
  int my[NCL];
#pragma unroll
  for (int c = 0; c < NCL; ++c) my[c] = myl[c];
#pragma unroll
  for (int c = 0; c < NCL; ++c)
    atomicAdd(&h[((0 * 2 + my[c]) * NCL + c) * 32 + cnt[c]], 1);
#pragma unroll
  for (int j = 10; j < 20; ++j) {
    const int* lr = labels + (size_t)nb[j] * NCL;
#pragma unroll
    for (int c = 0; c < NCL; ++c) cnt[c] += lr[c];
  }
#pragma unroll
  for (int c = 0; c < NCL; ++c)
    atomicAdd(&h[((1 * 2 + my[c]) * NCL + c) * 32 + cnt[c]], 1);
  __syncthreads();
  for (int i = tid; i < 2432; i += 256) {
    int v = h[i];
    if (v) atomicAdd(&ghist[i], v);
  }
}

// ---------------- conditional tables + priors ----------------
__global__ __launch_bounds__(256) void prep_kernel(const int* __restrict__ ghist,
                                                   float* __restrict__ cond,
                                                   float* __restrict__ prior) {
  __shared__ int cpos[NCL];
  int tid = threadIdx.x;
  if (tid < NCL) {
    int s = 0;
    for (int d = 0; d < 32; ++d) s += ghist[((0 * 2 + 1) * NCL + tid) * 32 + d];
    cpos[tid] = s;
    prior[tid] = (1.0f + (float)s) / (2.0f + (float)NTR);
  }
  __syncthreads();
  for (int i = tid; i < 2432; i += 256) {
    int cc = (i >> 5) % NCL;
    int pos = ((i >> 5) / NCL) & 1;
    int ki = i / (2 * NCL * 32);
    int k = ki ? 20 : 10;
    float num = 1.0f + (float)ghist[i];
    float den = (float)(k + 1) + (float)(pos ? cpos[cc] : (NTR - cpos[cc]));
    cond[i] = num / den;
  }
}

// ---------------- posterior output ----------------
__global__ __launch_bounds__(256) void out_kernel(const int* __restrict__ labels,
                                                  const int* __restrict__ nbrq,
                                                  const float* __restrict__ cond,
                                                  const float* __restrict__ prior,
                                                  float* __restrict__ out) {
  int q = blockIdx.x * 256 + threadIdx.x;  // 16 blocks -> 4096
  int nb[20];
#pragma unroll
  for (int j = 0; j < 20; ++j) nb[j] = nbrq[(size_t)q * 20 + j];
  int cnt[NCL], d10[NCL];
#pragma unroll
  for (int c = 0; c < NCL; ++c) cnt[c] = 0;
#pragma unroll
  for (int j = 0; j < 10; ++j) {
    const int* lr = labels + (size_t)nb[j] * NCL;
#pragma unroll
    for (int c = 0; c < NCL; ++c) cnt[c] += lr[c];
  }
#pragma unroll
  for (int c = 0; c < NCL; ++c) d10[c] = cnt[c];
#pragma unroll
  for (int j = 10; j < 20; ++j) {
    const int* lr = labels + (size_t)nb[j] * NCL;
#pragma unroll
    for (int c = 0; c < NCL; ++c) cnt[c] += lr[c];
  }
#pragma unroll
  for (int ki = 0; ki < 2; ++ki) {
#pragma unroll
    for (int c = 0; c < NCL; ++c) {
      int delta = ki ? cnt[c] : d10[c];
      float pr = prior[c];
      float pt = pr * cond[((ki * 2 + 1) * NCL + c) * 32 + delta];
      float pf = (1.0f - pr) * cond[((ki * 2 + 0) * NCL + c) * 32 + delta];
      out[((size_t)ki * NQR + q) * NCL + c] = pt / (pt + pf);
    }
  }
}

extern "C" void kernel_launch(void* const* d_in, const int* in_sizes, int n_in,
                              void* d_out, int out_size, void* d_ws, size_t ws_size,
                              hipStream_t stream) {
  const float* feat = (const float*)d_in[0];     // [4096,128]
  const float* train = (const float*)d_in[1];    // [16384,128]
  const int* labels = (const int*)d_in[2];       // [16384,19]
  float* out = (float*)d_out;                    // [2,4096,19]
  if (ws_size < WS_NEEDED) return;               // loud failure via poisoned output
  char* w = (char*)d_ws;
  float* rn = (float*)(w + OFF_RN);
  u16* qext = (u16*)(w + OFF_QEXT);
  u16* cext = (u16*)(w + OFF_CEXT);
  u16* fsn = (u16*)(w + OFF_FSN);
  int* nbrt = (int*)(w + OFF_NBRT);
  int* nbrq = (int*)(w + OFF_NBRQ);
  int* ghist = (int*)(w + OFF_HIST);
  float* cond = (float*)(w + OFF_COND);
  float* prior = (float*)(w + OFF_PRIOR);

  hipMemsetAsync(ghist, 0, 2432 * 4, stream);
  norms_kernel<<<80, 256, 0, stream>>>(train, feat, rn);
  ext_kernel<<<10240, 256, 0, stream>>>(train, feat, rn, qext, cext);
  filter_kernel<<<1280, 256, 0, stream>>>(qext, cext, fsn);
  rescore_kernel<<<20480, 192, 0, stream>>>(train, feat, rn, fsn, nbrt, nbrq);
  hist_kernel<<<64, 256, 0, stream>>>(labels, nbrt, ghist);
  prep_kernel<<<1, 256, 0, stream>>>(ghist, cond, prior);
  out_kernel<<<16, 256, 0, stream>>>(labels, nbrq, cond, prior, out);
}

// Round 9
// 860.151 us; speedup vs baseline: 4.7171x; 3.0190x over previous
//
#include <hip/hip_runtime.h>
#include <cstdint>
#include <cstddef>

#define NTR 16384
#define NQR 4096
#define NROW 20480
#define DF  128
#define NCL 19

typedef unsigned short u16;
typedef unsigned int u32;
typedef __attribute__((ext_vector_type(8))) short bf16x8;
typedef __attribute__((ext_vector_type(16))) float f32x16;

// ---- workspace layout (bytes) ----
#define OFF_RN    (size_t)0                  // float[20480]
#define OFF_QEXT  (size_t)81920              // u16[20480][144]
#define OFF_CEXT  (size_t)5980160            // u16[16384][144] (negated + hb dims)
#define OFF_FSN   (size_t)10698752           // u16[20480][192]
#define OFF_NBRT  (size_t)18563072           // int[16384][20]
#define OFF_NBRQ  (size_t)19873792           // int[4096][20]
#define OFF_HIST  (size_t)20201472           // int[2][2][19][32]
#define OFF_COND  (size_t)20211200           // float[2][2][19][32]
#define OFF_PRIOR (size_t)20220928           // float[19]
#define WS_NEEDED (size_t)20221008

// separately-rounded multiply (asm barrier blocks mul+add -> fma contraction)
__device__ __forceinline__ float mulr(float a, float b) {
  float m = a * b;
  asm volatile("" : "+v"(m));
  return m;
}

__device__ __forceinline__ u16 bf16_rne(float x) {
  union { float f; unsigned u; } v; v.f = x;
  unsigned r = (v.u + 0x7fffu + ((v.u >> 16) & 1u)) >> 16;
  return (u16)r;
}
__device__ __forceinline__ float bf16_f32(u16 h) {
  union { unsigned u; float f; } v; v.u = ((unsigned)h) << 16;
  return v.f;
}

__device__ __forceinline__ void gload_lds16(const void* g, void* lds) {
  __builtin_amdgcn_global_load_lds(
      (const __attribute__((address_space(1))) unsigned int*)g,
      (__attribute__((address_space(3))) unsigned int*)lds, 16, 0, 0);
}

// ---------------- row norms: exact reference realization (no FMA) ------------
__global__ __launch_bounds__(256) void norms_kernel(const float* __restrict__ train,
                                                    const float* __restrict__ feat,
                                                    float* __restrict__ rn) {
  int i = blockIdx.x * 256 + threadIdx.x;  // 80 blocks -> 20480
  const float* src = (i < NTR) ? (train + (size_t)i * DF) : (feat + (size_t)(i - NTR) * DF);
  float s = 0.0f;
  for (int k = 0; k < DF; ++k) {
    float x = src[k];
    s = s + mulr(x, x);
  }
  rn[i] = s;
}

// ---------------- ext: bf16 rows + metric K-extension ----------------
// qext[row][144]: [bf16(x_k)]*128, dim128=1.0, dim129=1.0, rest 0
// cext[c][144]:   [bf16(-x_k)]*128, dim128=hb_hi, dim129=hb_lo, rest 0
// where hb = 0.5*rn[c] + 256  ->  mfma(C,Q) = 256 + hb - dot  (positive metric)
__global__ __launch_bounds__(256) void ext_kernel(const float* __restrict__ train,
                                                  const float* __restrict__ feat,
                                                  const float* __restrict__ rn,
                                                  u16* __restrict__ qext,
                                                  u16* __restrict__ cext) {
  int row = blockIdx.x * 2 + (threadIdx.x >> 7);  // 10240 blocks -> 20480
  int k = threadIdx.x & 127;
  const float* srcp = (row < NTR) ? (train + (size_t)row * DF) : (feat + (size_t)(row - NTR) * DF);
  float x = srcp[k];
  u16 b = bf16_rne(x);
  qext[(size_t)row * 144 + k] = b;
  if (row < NTR) cext[(size_t)row * 144 + k] = (u16)(b ^ 0x8000u);
  if (k < 16) {
    qext[(size_t)row * 144 + 128 + k] = (k < 2) ? (u16)0x3F80 : (u16)0;
    if (row < NTR) {
      float hbf = 0.5f * rn[row] + 256.0f;
      u16 hi = bf16_rne(hbf);
      u16 lo = bf16_rne(hbf - bf16_f32(hi));
      cext[(size_t)row * 144 + 128 + k] = (k == 0) ? hi : ((k == 1) ? lo : (u16)0);
    }
  }
}

// ---------------- sorted top-16 insertion on packed u32 keys ----------------
__device__ __forceinline__ void insert16(u32 (&sd)[16], u32 key) {
#pragma unroll
  for (int j = 15; j >= 1; --j) {
    bool w = sd[j] > key;
    bool c = sd[j - 1] > key;
    if (w) sd[j] = c ? sd[j - 1] : key;
  }
  if (sd[0] > key) sd[0] = key;
}

// ---------------- FILTER: swapped 32x32x16 MFMA, q-in-regs, dbuf LDS ---------
// Grid 1280: slice = bid&7 (XCD-affine, 2048 cands L2-resident), rowblk = bid>>3.
// Block 256 thr = 4 waves (2 q-halves x 2 c-halves); wave = 64 q x 32 c.
// acc = mfma(cand_tile, query_tile): lane owns query col (l&31), 16 cand rows.
// Per n-tile(64c): 9 ds_read_b128 + 18 mfma + epilogue cmp/insert + 1 barrier.
__global__ __launch_bounds__(256, 2) void filter_kernel(const u16* __restrict__ qext,
                                                        const u16* __restrict__ cext,
                                                        u16* __restrict__ fsn) {
  __shared__ __align__(16) char smem[36864];  // cbuf[2]:16KB, hbuf[2]:2KB
  const int bid = blockIdx.x;
  const int slice = bid & 7, rowblk = bid >> 3;
  const int grow0 = rowblk * 128;
  const int cslice0 = slice * 2048;
  const int tid = threadIdx.x;
  const int wave = tid >> 6, lane = tid & 63;
  const int wq = wave >> 1, wc = wave & 1;
  const int l31 = lane & 31, h = lane >> 5;
  const char* qb = (const char*)qext;
  const char* cbg = (const char*)cext;

  // q fragments in registers: 2 q-tiles x 9 ksteps
  bf16x8 qf0[9], qf1[9];
  const int q0 = grow0 + wq * 64;
#pragma unroll
  for (int ks = 0; ks < 8; ++ks) {
    qf0[ks] = *(const bf16x8*)(qb + (size_t)(q0 + l31) * 288 + ks * 32 + h * 16);
    qf1[ks] = *(const bf16x8*)(qb + (size_t)(q0 + 32 + l31) * 288 + ks * 32 + h * 16);
  }
  qf0[8] = *(const bf16x8*)(qb + (size_t)(q0 + l31) * 288 + 256 + h * 16);
  qf1[8] = *(const bf16x8*)(qb + (size_t)(q0 + 32 + l31) * 288 + 256 + h * 16);

  u32 sd0[16], sd1[16];
#pragma unroll
  for (int t = 0; t < 16; ++t) { sd0[t] = 0x7F7FFFFFu; sd1[t] = 0x7F7FFFFFu; }

  // async stage of cand tile nt into buffer buf (source pre-swizzled, LDS linear)
  auto STAGE = [&](int buf, int nt) {
    const size_t c0 = (size_t)cslice0 + (size_t)nt * 64;
    char* cb = smem + buf * 16384;
    char* hb = smem + 32768 + buf * 2048;
#pragma unroll
    for (int j = 0; j < 4; ++j) {
      int I = wave + 4 * j;          // 0..15
      int G = I * 64 + lane;
      int r = G >> 4, g = G & 15;
      const char* src = cbg + (c0 + r) * 288 + ((g << 4) ^ ((r & 7) << 4));
      gload_lds16(src, cb + I * 1024);
    }
    if (wave < 2) {                  // 2 issues for hb dims (32B/row)
      int GG = wave * 64 + lane;
      int r = GG >> 1, half = GG & 1;
      const char* src = cbg + (c0 + r) * 288 + 256 + half * 16;
      gload_lds16(src, hb + wave * 1024);
    }
  };

  STAGE(0, 0);
  __syncthreads();

  const int crow = wc * 32 + l31;
  for (int nt = 0; nt < 32; ++nt) {
    const int cur = nt & 1;
    if (nt < 31) STAGE(cur ^ 1, nt + 1);

    const char* cbp = smem + cur * 16384 + crow * 256;
    const char* hbp = smem + 32768 + cur * 2048 + crow * 32 + h * 16;
    f32x16 acc0 = {0.f,0.f,0.f,0.f,0.f,0.f,0.f,0.f,0.f,0.f,0.f,0.f,0.f,0.f,0.f,0.f};
    f32x16 acc1 = {0.f,0.f,0.f,0.f,0.f,0.f,0.f,0.f,0.f,0.f,0.f,0.f,0.f,0.f,0.f,0.f};
#pragma unroll
    for (int ks = 0; ks < 8; ++ks) {
      bf16x8 cf = *(const bf16x8*)(cbp + ((ks * 32 + h * 16) ^ ((crow & 7) << 4)));
      acc0 = __builtin_amdgcn_mfma_f32_32x32x16_bf16(cf, qf0[ks], acc0, 0, 0, 0);
      acc1 = __builtin_amdgcn_mfma_f32_32x32x16_bf16(cf, qf1[ks], acc1, 0, 0, 0);
    }
    {
      bf16x8 cf = *(const bf16x8*)hbp;
      acc0 = __builtin_amdgcn_mfma_f32_32x32x16_bf16(cf, qf0[8], acc0, 0, 0, 0);
      acc1 = __builtin_amdgcn_mfma_f32_32x32x16_bf16(cf, qf1[8], acc1, 0, 0, 0);
    }

    // selection: key = (f32bits & ~0xFFF) | slice-local idx  (metric > 0)
    const int cb_idx = nt * 64 + wc * 32 + 4 * h;
    float th0 = __uint_as_float(sd0[15]);
    float th1 = __uint_as_float(sd1[15]);
#pragma unroll
    for (int j = 0; j < 16; ++j) {
      const int cl = cb_idx + (j & 3) + 8 * (j >> 2);
      float s0 = acc0[j];
      if (s0 < th0) {
        u32 key = (__float_as_uint(s0) & 0xFFFFF000u) | (u32)cl;
        insert16(sd0, key);
        th0 = __uint_as_float(sd0[15]);
      }
      float s1 = acc1[j];
      if (s1 < th1) {
        u32 key = (__float_as_uint(s1) & 0xFFFFF000u) | (u32)cl;
        insert16(sd1, key);
        th1 = __uint_as_float(sd1[15]);
      }
    }
    __syncthreads();  // staged next buf ready; reads of cur complete
  }

  // dump per-thread lists, then 4-way merge per row -> fsn[row][slice*24..+24]
  u32* md = (u32*)smem;
  {
    int b = tid * 32;
#pragma unroll
    for (int t = 0; t < 16; ++t) { md[b + t] = sd0[t]; md[b + 16 + t] = sd1[t]; }
  }
  __syncthreads();
  if (tid < 128) {
    const int r = tid;
    const int rwq = r >> 6, rqt = (r >> 5) & 1, rl = r & 31;
    const u32* L[4];
#pragma unroll
    for (int wcc = 0; wcc < 2; ++wcc)
#pragma unroll
      for (int hh = 0; hh < 2; ++hh)
        L[wcc * 2 + hh] = md + (size_t)(((rwq * 2 + wcc) * 64) + hh * 32 + rl) * 32 + rqt * 16;
    int p0 = 0, p1 = 0, p2 = 0, p3 = 0;
    size_t ob = (size_t)(grow0 + r) * 192 + (size_t)slice * 24;
    for (int t = 0; t < 24; ++t) {
      u32 k0 = (p0 < 16) ? L[0][p0] : 0xFFFFFFFFu;
      u32 k1 = (p1 < 16) ? L[1][p1] : 0xFFFFFFFFu;
      u32 k2 = (p2 < 16) ? L[2][p2] : 0xFFFFFFFFu;
      u32 k3 = (p3 < 16) ? L[3][p3] : 0xFFFFFFFFu;
      bool a01 = k0 <= k1; u32 kA = a01 ? k0 : k1;
      bool a23 = k2 <= k3; u32 kB = a23 ? k2 : k3;
      bool ab = kA <= kB;  u32 km = ab ? kA : kB;
      fsn[ob + t] = (u16)(cslice0 + (km & 0xFFFu));
      int win = ab ? (a01 ? 0 : 1) : (a23 ? 2 : 3);
      p0 += (win == 0); p1 += (win == 1); p2 += (win == 2); p3 += (win == 3);
    }
  }
}

// ---------------- RESCORE: exact no-FMA chain on 192 cands/row, rank-select --
// v3: float4 candidate loads with one-chunk-ahead prefetch + float4 LDS query
// reads; the ascending-k add chain (data-dependent on s) is order-preserved,
// so scores are bit-identical to the verified realization.
__global__ __launch_bounds__(192) void rescore_kernel(const float* __restrict__ train,
                                                      const float* __restrict__ feat,
                                                      const float* __restrict__ rn,
                                                      const u16* __restrict__ fsn,
                                                      int* __restrict__ nbrt,
                                                      int* __restrict__ nbrq) {
  __shared__ __align__(16) float rowf[DF];
  __shared__ __align__(16) float sc[192];
  __shared__ __align__(16) int sidx[192];
  const int row = blockIdx.x;  // 20480 blocks
  const int t = threadIdx.x;
  const float* src = (row < NTR) ? (train + (size_t)row * DF) : (feat + (size_t)(row - NTR) * DF);
  if (t < DF) rowf[t] = src[t];
  __syncthreads();
  {
    int ci = (int)fsn[(size_t)row * 192 + t];
    if (ci >= NTR) ci = NTR - 1;  // defensive (bug -> absmax, not fault)
    const float* tv = train + (size_t)ci * DF;
    float4 b0 = *(const float4*)(tv + 0);
    float4 b1 = *(const float4*)(tv + 4);
    float4 b2 = *(const float4*)(tv + 8);
    float4 b3 = *(const float4*)(tv + 12);
    float s = 0.0f;
#pragma unroll
    for (int ch = 0; ch < 8; ++ch) {
      float4 n0, n1, n2, n3;
      if (ch < 7) {
        const float* nx = tv + (ch + 1) * 16;
        n0 = *(const float4*)(nx + 0);
        n1 = *(const float4*)(nx + 4);
        n2 = *(const float4*)(nx + 8);
        n3 = *(const float4*)(nx + 12);
      }
      float4 q0 = *(const float4*)&rowf[ch * 16 + 0];
      float4 q1 = *(const float4*)&rowf[ch * 16 + 4];
      float4 q2 = *(const float4*)&rowf[ch * 16 + 8];
      float4 q3 = *(const float4*)&rowf[ch * 16 + 12];
      // strict ascending-k chain (order fixed by the dependence on s)
      s = s + mulr(q0.x, b0.x); s = s + mulr(q0.y, b0.y);
      s = s + mulr(q0.z, b0.z); s = s + mulr(q0.w, b0.w);
      s = s + mulr(q1.x, b1.x); s = s + mulr(q1.y, b1.y);
      s = s + mulr(q1.z, b1.z); s = s + mulr(q1.w, b1.w);
      s = s + mulr(q2.x, b2.x); s = s + mulr(q2.y, b2.y);
      s = s + mulr(q2.z, b2.z); s = s + mulr(q2.w, b2.w);
      s = s + mulr(q3.x, b3.x); s = s + mulr(q3.y, b3.y);
      s = s + mulr(q3.z, b3.z); s = s + mulr(q3.w, b3.w);
      if (ch < 7) { b0 = n0; b1 = n1; b2 = n2; b3 = n3; }
    }
    float t1 = rn[row] + rn[ci];
    sc[t] = t1 - 2.0f * s;
    sidx[t] = ci;
  }
  __syncthreads();
  {
    float dm = sc[t];
    int im = sidx[t];
    int rank = 0;
#pragma unroll 4
    for (int i = 0; i < 192; i += 4) {
      float4 d4 = *(const float4*)&sc[i];
      int4 i4 = *(const int4*)&sidx[i];
      rank += (d4.x < dm || (d4.x == dm && i4.x < im));
      rank += (d4.y < dm || (d4.y == dm && i4.y < im));
      rank += (d4.z < dm || (d4.z == dm && i4.z < im));
      rank += (d4.w < dm || (d4.w == dm && i4.w < im));
    }
    if (rank < 20) {
      int* outp = (row < NTR) ? (nbrt + (size_t)row * 20) : (nbrq + (size_t)(row - NTR) * 20);
      outp[rank] = im;
    }
  }
}

// ---------------- label-count histograms (k=10 and k=20) ----------------
__global__ __launch_bounds__(256) void hist_kernel(const int* __restrict__ labels,
                                                   const int* __restrict__ nbrt,
                                                   int* __restrict__ ghist) {
  __shared__ int h[2432];
  int tid = threadIdx.x;
  for (int i = tid; i < 2432; i += 256) h[i] = 0;
  __syncthreads();
  int row = blockIdx.x * 256 + tid;  // 64 blocks -> 16384
  int nb[20];
#pragma unroll
  for (int j = 0; j < 20; ++j) nb[j] = nbrt[(size_t)row * 20 + j];
  int cnt[NCL];
#pragma unroll
  for (int c = 0; c < NCL; ++c) cnt[c] = 0;
#pragma unroll
  for (int j = 0; j < 10; ++j) {
    const int* lr = labels + (size_t)nb[j] * NCL;
#pragma unroll
    for (int c = 0; c < NCL; ++c) cnt[c] += lr[c];
  }
  const int* myl = labels + (size_t)row * NCL;
  int my[NCL];
#pragma unroll
  for (int c = 0; c < NCL; ++c) my[c] = myl[c];
#pragma unroll
  for (int c = 0; c < NCL; ++c)
    atomicAdd(&h[((0 * 2 + my[c]) * NCL + c) * 32 + cnt[c]], 1);
#pragma unroll
  for (int j = 10; j < 20; ++j) {
    const int* lr = labels + (size_t)nb[j] * NCL;
#pragma unroll
    for (int c = 0; c < NCL; ++c) cnt[c] += lr[c];
  }
#pragma unroll
  for (int c = 0; c < NCL; ++c)
    atomicAdd(&h[((1 * 2 + my[c]) * NCL + c) * 32 + cnt[c]], 1);
  __syncthreads();
  for (int i = tid; i < 2432; i += 256) {
    int v = h[i];
    if (v) atomicAdd(&ghist[i], v);
  }
}

// ---------------- conditional tables + priors ----------------
__global__ __launch_bounds__(256) void prep_kernel(const int* __restrict__ ghist,
                                                   float* __restrict__ cond,
                                                   float* __restrict__ prior) {
  __shared__ int cpos[NCL];
  int tid = threadIdx.x;
  if (tid < NCL) {
    int s = 0;
    for (int d = 0; d < 32; ++d) s += ghist[((0 * 2 + 1) * NCL + tid) * 32 + d];
    cpos[tid] = s;
    prior[tid] = (1.0f + (float)s) / (2.0f + (float)NTR);
  }
  __syncthreads();
  for (int i = tid; i < 2432; i += 256) {
    int cc = (i >> 5) % NCL;
    int pos = ((i >> 5) / NCL) & 1;
    int ki = i / (2 * NCL * 32);
    int k = ki ? 20 : 10;
    float num = 1.0f + (float)ghist[i];
    float den = (float)(k + 1) + (float)(pos ? cpos[cc] : (NTR - cpos[cc]));
    cond[i] = num / den;
  }
}

// ---------------- posterior output ----------------
__global__ __launch_bounds__(256) void out_kernel(const int* __restrict__ labels,
                                                  const int* __restrict__ nbrq,
                                                  const float* __restrict__ cond,
                                                  const float* __restrict__ prior,
                                                  float* __restrict__ out) {
  int q = blockIdx.x * 256 + threadIdx.x;  // 16 blocks -> 4096
  int nb[20];
#pragma unroll
  for (int j = 0; j < 20; ++j) nb[j] = nbrq[(size_t)q * 20 + j];
  int cnt[NCL], d10[NCL];
#pragma unroll
  for (int c = 0; c < NCL; ++c) cnt[c] = 0;
#pragma unroll
  for (int j = 0; j < 10; ++j) {
    const int* lr = labels + (size_t)nb[j] * NCL;
#pragma unroll
    for (int c = 0; c < NCL; ++c) cnt[c] += lr[c];
  }
#pragma unroll
  for (int c = 0; c < NCL; ++c) d10[c] = cnt[c];
#pragma unroll
  for (int j = 10; j < 20; ++j) {
    const int* lr = labels + (size_t)nb[j] * NCL;
#pragma unroll
    for (int c = 0; c < NCL; ++c) cnt[c] += lr[c];
  }
#pragma unroll
  for (int ki = 0; ki < 2; ++ki) {
#pragma unroll
    for (int c = 0; c < NCL; ++c) {
      int delta = ki ? cnt[c] : d10[c];
      float pr = prior[c];
      float pt = pr * cond[((ki * 2 + 1) * NCL + c) * 32 + delta];
      float pf = (1.0f - pr) * cond[((ki * 2 + 0) * NCL + c) * 32 + delta];
      out[((size_t)ki * NQR + q) * NCL + c] = pt / (pt + pf);
    }
  }
}

extern "C" void kernel_launch(void* const* d_in, const int* in_sizes, int n_in,
                              void* d_out, int out_size, void* d_ws, size_t ws_size,
                              hipStream_t stream) {
  const float* feat = (const float*)d_in[0];     // [4096,128]
  const float* train = (const float*)d_in[1];    // [16384,128]
  const int* labels = (const int*)d_in[2];       // [16384,19]
  float* out = (float*)d_out;                    // [2,4096,19]
  if (ws_size < WS_NEEDED) return;               // loud failure via poisoned output
  char* w = (char*)d_ws;
  float* rn = (float*)(w + OFF_RN);
  u16* qext = (u16*)(w + OFF_QEXT);
  u16* cext = (u16*)(w + OFF_CEXT);
  u16* fsn = (u16*)(w + OFF_FSN);
  int* nbrt = (int*)(w + OFF_NBRT);
  int* nbrq = (int*)(w + OFF_NBRQ);
  int* ghist = (int*)(w + OFF_HIST);
  float* cond = (float*)(w + OFF_COND);
  float* prior = (float*)(w + OFF_PRIOR);

  hipMemsetAsync(ghist, 0, 2432 * 4, stream);
  norms_kernel<<<80, 256, 0, stream>>>(train, feat, rn);
  ext_kernel<<<10240, 256, 0, stream>>>(train, feat, rn, qext, cext);
  filter_kernel<<<1280, 256, 0, stream>>>(qext, cext, fsn);
  rescore_kernel<<<20480, 192, 0, stream>>>(train, feat, rn, fsn, nbrt, nbrq);
  hist_kernel<<<64, 256, 0, stream>>>(labels, nbrt, ghist);
  prep_kernel<<<1, 256, 0, stream>>>(ghist, cond, prior);
  out_kernel<<<16, 256, 0, stream>>>(labels, nbrq, cond, prior, out);
}

// Round 10
// 744.765 us; speedup vs baseline: 5.4479x; 1.1549x over previous
//
#include <hip/hip_runtime.h>
#include <cstdint>
#include <cstddef>

#define NTR 16384
#define NQR 4096
#define NROW 20480
#define DF  128
#define NCL 19

typedef unsigned short u16;
typedef unsigned int u32;
typedef __attribute__((ext_vector_type(8))) short bf16x8;
typedef __attribute__((ext_vector_type(16))) float f32x16;

// ---- workspace layout (bytes) ----
#define OFF_RN    (size_t)0                  // float[20480]
#define OFF_QEXT  (size_t)81920              // u16[20480][144]
#define OFF_CEXT  (size_t)5980160            // u16[16384][144] (negated + hb dims)
#define OFF_FSN   (size_t)10698752           // u16[20480][192]
#define OFF_NBRT  (size_t)18563072           // int[16384][20]
#define OFF_NBRQ  (size_t)19873792           // int[4096][20]
#define OFF_HIST  (size_t)20201472           // int[2][2][19][32]
#define OFF_COND  (size_t)20211200           // float[2][2][19][32]
#define OFF_PRIOR (size_t)20220928           // float[19]
#define WS_NEEDED (size_t)20221008

// separately-rounded multiply (asm barrier blocks mul+add -> fma contraction)
__device__ __forceinline__ float mulr(float a, float b) {
  float m = a * b;
  asm volatile("" : "+v"(m));
  return m;
}

__device__ __forceinline__ u16 bf16_rne(float x) {
  union { float f; unsigned u; } v; v.f = x;
  unsigned r = (v.u + 0x7fffu + ((v.u >> 16) & 1u)) >> 16;
  return (u16)r;
}
__device__ __forceinline__ float bf16_f32(u16 h) {
  union { unsigned u; float f; } v; v.u = ((unsigned)h) << 16;
  return v.f;
}

__device__ __forceinline__ void gload_lds16(const void* g, void* lds) {
  __builtin_amdgcn_global_load_lds(
      (const __attribute__((address_space(1))) unsigned int*)g,
      (__attribute__((address_space(3))) unsigned int*)lds, 16, 0, 0);
}

// ---------------- row norms: exact reference realization (no FMA) ------------
__global__ __launch_bounds__(256) void norms_kernel(const float* __restrict__ train,
                                                    const float* __restrict__ feat,
                                                    float* __restrict__ rn) {
  int i = blockIdx.x * 256 + threadIdx.x;  // 80 blocks -> 20480
  const float* src = (i < NTR) ? (train + (size_t)i * DF) : (feat + (size_t)(i - NTR) * DF);
  float s = 0.0f;
  for (int k = 0; k < DF; ++k) {
    float x = src[k];
    s = s + mulr(x, x);
  }
  rn[i] = s;
}

// ---------------- ext: bf16 rows + metric K-extension ----------------
// qext[row][144]: [bf16(x_k)]*128, dim128=1.0, dim129=1.0, rest 0
// cext[c][144]:   [bf16(-x_k)]*128, dim128=hb_hi, dim129=hb_lo, rest 0
// where hb = 0.5*rn[c] + 256  ->  mfma(C,Q) = 256 + hb - dot  (positive metric)
__global__ __launch_bounds__(256) void ext_kernel(const float* __restrict__ train,
                                                  const float* __restrict__ feat,
                                                  const float* __restrict__ rn,
                                                  u16* __restrict__ qext,
                                                  u16* __restrict__ cext) {
  int row = blockIdx.x * 2 + (threadIdx.x >> 7);  // 10240 blocks -> 20480
  int k = threadIdx.x & 127;
  const float* srcp = (row < NTR) ? (train + (size_t)row * DF) : (feat + (size_t)(row - NTR) * DF);
  float x = srcp[k];
  u16 b = bf16_rne(x);
  qext[(size_t)row * 144 + k] = b;
  if (row < NTR) cext[(size_t)row * 144 + k] = (u16)(b ^ 0x8000u);
  if (k < 16) {
    qext[(size_t)row * 144 + 128 + k] = (k < 2) ? (u16)0x3F80 : (u16)0;
    if (row < NTR) {
      float hbf = 0.5f * rn[row] + 256.0f;
      u16 hi = bf16_rne(hbf);
      u16 lo = bf16_rne(hbf - bf16_f32(hi));
      cext[(size_t)row * 144 + 128 + k] = (k == 0) ? hi : ((k == 1) ? lo : (u16)0);
    }
  }
}

// ---------------- sorted top-16 insertion on packed u32 keys ----------------
__device__ __forceinline__ void insert16(u32 (&sd)[16], u32 key) {
#pragma unroll
  for (int j = 15; j >= 1; --j) {
    bool w = sd[j] > key;
    bool c = sd[j - 1] > key;
    if (w) sd[j] = c ? sd[j - 1] : key;
  }
  if (sd[0] > key) sd[0] = key;
}

// ---------------- FILTER: swapped 32x32x16 MFMA, 1 q-subtile/wave ------------
// Grid 2560: slice = bid&7 (XCD-affine, cand slice 590KB L2-resident),
// rowblk = bid>>3 (64 q rows/block). Block 256 thr = 4 waves (wq x wc).
// Wave: q-subtile 32 rows x cand-subtile 32 rows; acc = mfma(cand, q):
// lane owns q col (l&31); 16 cand rows in acc regs. Low register footprint
// (qf 36 + sd 16 + acc 16) -> no scratch spill (r9 spilled at 150+ demand).
__global__ __launch_bounds__(256, 3) void filter_kernel(const u16* __restrict__ qext,
                                                        const u16* __restrict__ cext,
                                                        u16* __restrict__ fsn) {
  __shared__ __align__(16) char smem[36864];  // cbuf[2]:16KB, hbuf[2]:2KB
  const int bid = blockIdx.x;
  const int slice = bid & 7, rowblk = bid >> 3;
  const int grow0 = rowblk * 64;
  const int cslice0 = slice * 2048;
  const int tid = threadIdx.x;
  const int wave = tid >> 6, lane = tid & 63;
  const int wq = wave >> 1, wc = wave & 1;
  const int l31 = lane & 31, h = lane >> 5;
  const char* qb = (const char*)qext;
  const char* cbg = (const char*)cext;

  // q fragments in registers: 9 ksteps for this wave's 32-row q-subtile
  bf16x8 qf[9];
  const int qrow = grow0 + wq * 32 + l31;
#pragma unroll
  for (int ks = 0; ks < 8; ++ks)
    qf[ks] = *(const bf16x8*)(qb + (size_t)qrow * 288 + ks * 32 + h * 16);
  qf[8] = *(const bf16x8*)(qb + (size_t)qrow * 288 + 256 + h * 16);

  u32 sd[16];
#pragma unroll
  for (int t = 0; t < 16; ++t) sd[t] = 0x7F7FFFFFu;

  // async stage of cand tile nt into buffer buf (source pre-swizzled, LDS linear)
  auto STAGE = [&](int buf, int nt) {
    const size_t c0 = (size_t)cslice0 + (size_t)nt * 64;
    char* cb = smem + buf * 16384;
    char* hb = smem + 32768 + buf * 2048;
#pragma unroll
    for (int j = 0; j < 4; ++j) {
      int I = wave + 4 * j;          // 0..15
      int G = I * 64 + lane;
      int r = G >> 4, g = G & 15;
      const char* src = cbg + (c0 + r) * 288 + ((g << 4) ^ ((r & 7) << 4));
      gload_lds16(src, cb + I * 1024);
    }
    if (wave < 2) {                  // 2 issues for hb dims (32B/row)
      int GG = wave * 64 + lane;
      int r = GG >> 1, half = GG & 1;
      const char* src = cbg + (c0 + r) * 288 + 256 + half * 16;
      gload_lds16(src, hb + wave * 1024);
    }
  };

  STAGE(0, 0);
  __syncthreads();

  const int crow = wc * 32 + l31;
  for (int nt = 0; nt < 32; ++nt) {
    const int cur = nt & 1;
    if (nt < 31) STAGE(cur ^ 1, nt + 1);

    const char* cbp = smem + cur * 16384 + crow * 256;
    const char* hbp = smem + 32768 + cur * 2048 + crow * 32 + h * 16;
    f32x16 acc = {0.f,0.f,0.f,0.f,0.f,0.f,0.f,0.f,0.f,0.f,0.f,0.f,0.f,0.f,0.f,0.f};
#pragma unroll
    for (int ks = 0; ks < 8; ++ks) {
      bf16x8 cf = *(const bf16x8*)(cbp + ((ks * 32 + h * 16) ^ ((crow & 7) << 4)));
      acc = __builtin_amdgcn_mfma_f32_32x32x16_bf16(cf, qf[ks], acc, 0, 0, 0);
    }
    {
      bf16x8 cf = *(const bf16x8*)hbp;
      acc = __builtin_amdgcn_mfma_f32_32x32x16_bf16(cf, qf[8], acc, 0, 0, 0);
    }

    // selection: key = (f32bits & ~0xFFF) | slice-local idx  (metric > 0)
    const int cb_idx = nt * 64 + wc * 32 + 4 * h;
    float th = __uint_as_float(sd[15]);
#pragma unroll
    for (int j = 0; j < 16; ++j) {
      const int cl = cb_idx + (j & 3) + 8 * (j >> 2);
      float s0 = acc[j];
      if (s0 < th) {
        u32 key = (__float_as_uint(s0) & 0xFFFFF000u) | (u32)cl;
        insert16(sd, key);
        th = __uint_as_float(sd[15]);
      }
    }
    __syncthreads();  // staged next buf ready; reads of cur complete
  }

  // dump per-thread lists, then 4-way merge per row -> fsn[row][slice*24..+24]
  u32* md = (u32*)smem;
  {
    int b = tid * 16;
#pragma unroll
    for (int t = 0; t < 16; ++t) md[b + t] = sd[t];
  }
  __syncthreads();
  if (tid < 64) {
    const int r = tid;                 // row within block (wq*32 + qcol)
    const int rwq = r >> 5, rl = r & 31;
    const u32* L[4];
#pragma unroll
    for (int wcc = 0; wcc < 2; ++wcc)
#pragma unroll
      for (int hh = 0; hh < 2; ++hh)
        L[wcc * 2 + hh] = md + (size_t)((rwq * 2 + wcc) * 64 + hh * 32 + rl) * 16;
    int p0 = 0, p1 = 0, p2 = 0, p3 = 0;
    size_t ob = (size_t)(grow0 + r) * 192 + (size_t)slice * 24;
    for (int t = 0; t < 24; ++t) {
      u32 k0 = (p0 < 16) ? L[0][p0] : 0xFFFFFFFFu;
      u32 k1 = (p1 < 16) ? L[1][p1] : 0xFFFFFFFFu;
      u32 k2 = (p2 < 16) ? L[2][p2] : 0xFFFFFFFFu;
      u32 k3 = (p3 < 16) ? L[3][p3] : 0xFFFFFFFFu;
      bool a01 = k0 <= k1; u32 kA = a01 ? k0 : k1;
      bool a23 = k2 <= k3; u32 kB = a23 ? k2 : k3;
      bool ab = kA <= kB;  u32 km = ab ? kA : kB;
      fsn[ob + t] = (u16)(cslice0 + (km & 0xFFFu));
      int win = ab ? (a01 ? 0 : 1) : (a23 ? 2 : 3);
      p0 += (win == 0); p1 += (win == 1); p2 += (win == 2); p3 += (win == 3);
    }
  }
}

// ---------------- RESCORE: exact no-FMA chain on 192 cands/row, rank-select --
// float4 candidate loads with one-chunk-ahead prefetch + float4 LDS query
// reads; the ascending-k add chain (data-dependent on s) is order-preserved,
// so scores are bit-identical to the verified realization.
__global__ __launch_bounds__(192) void rescore_kernel(const float* __restrict__ train,
                                                      const float* __restrict__ feat,
                                                      const float* __restrict__ rn,
                                                      const u16* __restrict__ fsn,
                                                      int* __restrict__ nbrt,
                                                      int* __restrict__ nbrq) {
  __shared__ __align__(16) float rowf[DF];
  __shared__ __align__(16) float sc[192];
  __shared__ __align__(16) int sidx[192];
  const int row = blockIdx.x;  // 20480 blocks
  const int t = threadIdx.x;
  const float* src = (row < NTR) ? (train + (size_t)row * DF) : (feat + (size_t)(row - NTR) * DF);
  if (t < DF) rowf[t] = src[t];
  __syncthreads();
  {
    int ci = (int)fsn[(size_t)row * 192 + t];
    if (ci >= NTR) ci = NTR - 1;  // defensive (bug -> absmax, not fault)
    const float* tv = train + (size_t)ci * DF;
    float4 b0 = *(const float4*)(tv + 0);
    float4 b1 = *(const float4*)(tv + 4);
    float4 b2 = *(const float4*)(tv + 8);
    float4 b3 = *(const float4*)(tv + 12);
    float s = 0.0f;
#pragma unroll
    for (int ch = 0; ch < 8; ++ch) {
      float4 n0, n1, n2, n3;
      if (ch < 7) {
        const float* nx = tv + (ch + 1) * 16;
        n0 = *(const float4*)(nx + 0);
        n1 = *(const float4*)(nx + 4);
        n2 = *(const float4*)(nx + 8);
        n3 = *(const float4*)(nx + 12);
      }
      float4 q0 = *(const float4*)&rowf[ch * 16 + 0];
      float4 q1 = *(const float4*)&rowf[ch * 16 + 4];
      float4 q2 = *(const float4*)&rowf[ch * 16 + 8];
      float4 q3 = *(const float4*)&rowf[ch * 16 + 12];
      // strict ascending-k chain (order fixed by the dependence on s)
      s = s + mulr(q0.x, b0.x); s = s + mulr(q0.y, b0.y);
      s = s + mulr(q0.z, b0.z); s = s + mulr(q0.w, b0.w);
      s = s + mulr(q1.x, b1.x); s = s + mulr(q1.y, b1.y);
      s = s + mulr(q1.z, b1.z); s = s + mulr(q1.w, b1.w);
      s = s + mulr(q2.x, b2.x); s = s + mulr(q2.y, b2.y);
      s = s + mulr(q2.z, b2.z); s = s + mulr(q2.w, b2.w);
      s = s + mulr(q3.x, b3.x); s = s + mulr(q3.y, b3.y);
      s = s + mulr(q3.z, b3.z); s = s + mulr(q3.w, b3.w);
      if (ch < 7) { b0 = n0; b1 = n1; b2 = n2; b3 = n3; }
    }
    float t1 = rn[row] + rn[ci];
    sc[t] = t1 - 2.0f * s;
    sidx[t] = ci;
  }
  __syncthreads();
  {
    float dm = sc[t];
    int im = sidx[t];
    int rank = 0;
#pragma unroll 4
    for (int i = 0; i < 192; i += 4) {
      float4 d4 = *(const float4*)&sc[i];
      int4 i4 = *(const int4*)&sidx[i];
      rank += (d4.x < dm || (d4.x == dm && i4.x < im));
      rank += (d4.y < dm || (d4.y == dm && i4.y < im));
      rank += (d4.z < dm || (d4.z == dm && i4.z < im));
      rank += (d4.w < dm || (d4.w == dm && i4.w < im));
    }
    if (rank < 20) {
      int* outp = (row < NTR) ? (nbrt + (size_t)row * 20) : (nbrq + (size_t)(row - NTR) * 20);
      outp[rank] = im;
    }
  }
}

// ---------------- label-count histograms (k=10 and k=20) ----------------
__global__ __launch_bounds__(256) void hist_kernel(const int* __restrict__ labels,
                                                   const int* __restrict__ nbrt,
                                                   int* __restrict__ ghist) {
  __shared__ int h[2432];
  int tid = threadIdx.x;
  for (int i = tid; i < 2432; i += 256) h[i] = 0;
  __syncthreads();
  int row = blockIdx.x * 256 + tid;  // 64 blocks -> 16384
  int nb[20];
#pragma unroll
  for (int j = 0; j < 20; ++j) nb[j] = nbrt[(size_t)row * 20 + j];
  int cnt[NCL];
#pragma unroll
  for (int c = 0; c < NCL; ++c) cnt[c] = 0;
#pragma unroll
  for (int j = 0; j < 10; ++j) {
    const int* lr = labels + (size_t)nb[j] * NCL;
#pragma unroll
    for (int c = 0; c < NCL; ++c) cnt[c] += lr[c];
  }
  const int* myl = labels + (size_t)row * NCL;
  int my[NCL];
#pragma unroll
  for (int c = 0; c < NCL; ++c) my[c] = myl[c];
#pragma unroll
  for (int c = 0; c < NCL; ++c)
    atomicAdd(&h[((0 * 2 + my[c]) * NCL + c) * 32 + cnt[c]], 1);
#pragma unroll
  for (int j = 10; j < 20; ++j) {
    const int* lr = labels + (size_t)nb[j] * NCL;
#pragma unroll
    for (int c = 0; c < NCL; ++c) cnt[c] += lr[c];
  }
#pragma unroll
  for (int c = 0; c < NCL; ++c)
    atomicAdd(&h[((1 * 2 + my[c]) * NCL + c) * 32 + cnt[c]], 1);
  __syncthreads();
  for (int i = tid; i < 2432; i += 256) {
    int v = h[i];
    if (v) atomicAdd(&ghist[i], v);
  }
}

// ---------------- conditional tables + priors ----------------
__global__ __launch_bounds__(256) void prep_kernel(const int* __restrict__ ghist,
                                                   float* __restrict__ cond,
                                                   float* __restrict__ prior) {
  __shared__ int cpos[NCL];
  int tid = threadIdx.x;
  if (tid < NCL) {
    int s = 0;
    for (int d = 0; d < 32; ++d) s += ghist[((0 * 2 + 1) * NCL + tid) * 32 + d];
    cpos[tid] = s;
    prior[tid] = (1.0f + (float)s) / (2.0f + (float)NTR);
  }
  __syncthreads();
  for (int i = tid; i < 2432; i += 256) {
    int cc = (i >> 5) % NCL;
    int pos = ((i >> 5) / NCL) & 1;
    int ki = i / (2 * NCL * 32);
    int k = ki ? 20 : 10;
    float num = 1.0f + (float)ghist[i];
    float den = (float)(k + 1) + (float)(pos ? cpos[cc] : (NTR - cpos[cc]));
    cond[i] = num / den;
  }
}

// ---------------- posterior output ----------------
__global__ __launch_bounds__(256) void out_kernel(const int* __restrict__ labels,
                                                  const int* __restrict__ nbrq,
                                                  const float* __restrict__ cond,
                                                  const float* __restrict__ prior,
                                                  float* __restrict__ out) {
  int q = blockIdx.x * 256 + threadIdx.x;  // 16 blocks -> 4096
  int nb[20];
#pragma unroll
  for (int j = 0; j < 20; ++j) nb[j] = nbrq[(size_t)q * 20 + j];
  int cnt[NCL], d10[NCL];
#pragma unroll
  for (int c = 0; c < NCL; ++c) cnt[c] = 0;
#pragma unroll
  for (int j = 0; j < 10; ++j) {
    const int* lr = labels + (size_t)nb[j] * NCL;
#pragma unroll
    for (int c = 0; c < NCL; ++c) cnt[c] += lr[c];
  }
#pragma unroll
  for (int c = 0; c < NCL; ++c) d10[c] = cnt[c];
#pragma unroll
  for (int j = 10; j < 20; ++j) {
    const int* lr = labels + (size_t)nb[j] * NCL;
#pragma unroll
    for (int c = 0; c < NCL; ++c) cnt[c] += lr[c];
  }
#pragma unroll
  for (int ki = 0; ki < 2; ++ki) {
#pragma unroll
    for (int c = 0; c < NCL; ++c) {
      int delta = ki ? cnt[c] : d10[c];
      float pr = prior[c];
      float pt = pr * cond[((ki * 2 + 1) * NCL + c) * 32 + delta];
      float pf = (1.0f - pr) * cond[((ki * 2 + 0) * NCL + c) * 32 + delta];
      out[((size_t)ki * NQR + q) * NCL + c] = pt / (pt + pf);
    }
  }
}

extern "C" void kernel_launch(void* const* d_in, const int* in_sizes, int n_in,
                              void* d_out, int out_size, void* d_ws, size_t ws_size,
                              hipStream_t stream) {
  const float* feat = (const float*)d_in[0];     // [4096,128]
  const float* train = (const float*)d_in[1];    // [16384,128]
  const int* labels = (const int*)d_in[2];       // [16384,19]
  float* out = (float*)d_out;                    // [2,4096,19]
  if (ws_size < WS_NEEDED) return;               // loud failure via poisoned output
  char* w = (char*)d_ws;
  float* rn = (float*)(w + OFF_RN);
  u16* qext = (u16*)(w + OFF_QEXT);
  u16* cext = (u16*)(w + OFF_CEXT);
  u16* fsn = (u16*)(w + OFF_FSN);
  int* nbrt = (int*)(w + OFF_NBRT);
  int* nbrq = (int*)(w + OFF_NBRQ);
  int* ghist = (int*)(w + OFF_HIST);
  float* cond = (float*)(w + OFF_COND);
  float* prior = (float*)(w + OFF_PRIOR);

  hipMemsetAsync(ghist, 0, 2432 * 4, stream);
  norms_kernel<<<80, 256, 0, stream>>>(train, feat, rn);
  ext_kernel<<<10240, 256, 0, stream>>>(train, feat, rn, qext, cext);
  filter_kernel<<<2560, 256, 0, stream>>>(qext, cext, fsn);
  rescore_kernel<<<20480, 192, 0, stream>>>(train, feat, rn, fsn, nbrt, nbrq);
  hist_kernel<<<64, 256, 0, stream>>>(labels, nbrt, ghist);
  prep_kernel<<<1, 256, 0, stream>>>(ghist, cond, prior);
  out_kernel<<<16, 256, 0, stream>>>(labels, nbrq, cond, prior, out);
}

// Round 11
// 536.672 us; speedup vs baseline: 7.5603x; 1.3877x over previous
//
#include <hip/hip_runtime.h>
#include <cstdint>
#include <cstddef>

#define NTR 16384
#define NQR 4096
#define NROW 20480
#define DF  128
#define NCL 19

typedef unsigned short u16;
typedef unsigned int u32;
typedef __attribute__((ext_vector_type(8))) short bf16x8;
typedef __attribute__((ext_vector_type(16))) float f32x16;

// ---- workspace layout (bytes) ----
#define OFF_RN    (size_t)0                  // float[20480]
#define OFF_QEXT  (size_t)81920              // u16[20480][144]
#define OFF_CEXT  (size_t)5980160            // u16[16384][144] (negated + hb dims)
#define OFF_FSN   (size_t)10698752           // u16[20480][192]
#define OFF_NBRT  (size_t)18563072           // int[16384][20]
#define OFF_NBRQ  (size_t)19873792           // int[4096][20]
#define OFF_HIST  (size_t)20201472           // int[2][2][19][32]
#define OFF_COND  (size_t)20211200           // float[2][2][19][32]
#define OFF_PRIOR (size_t)20220928           // float[19]
#define WS_NEEDED (size_t)20221008

// separately-rounded multiply (asm barrier blocks mul+add -> fma contraction)
__device__ __forceinline__ float mulr(float a, float b) {
  float m = a * b;
  asm volatile("" : "+v"(m));
  return m;
}

__device__ __forceinline__ u16 bf16_rne(float x) {
  union { float f; unsigned u; } v; v.f = x;
  unsigned r = (v.u + 0x7fffu + ((v.u >> 16) & 1u)) >> 16;
  return (u16)r;
}
__device__ __forceinline__ float bf16_f32(u16 h) {
  union { unsigned u; float f; } v; v.u = ((unsigned)h) << 16;
  return v.f;
}

__device__ __forceinline__ void gload_lds16(const void* g, void* lds) {
  __builtin_amdgcn_global_load_lds(
      (const __attribute__((address_space(1))) unsigned int*)g,
      (__attribute__((address_space(3))) unsigned int*)lds, 16, 0, 0);
}

// ---------------- row norms: exact reference realization (no FMA) ------------
__global__ __launch_bounds__(256) void norms_kernel(const float* __restrict__ train,
                                                    const float* __restrict__ feat,
                                                    float* __restrict__ rn) {
  int i = blockIdx.x * 256 + threadIdx.x;  // 80 blocks -> 20480
  const float* src = (i < NTR) ? (train + (size_t)i * DF) : (feat + (size_t)(i - NTR) * DF);
  float s = 0.0f;
  for (int k = 0; k < DF; ++k) {
    float x = src[k];
    s = s + mulr(x, x);
  }
  rn[i] = s;
}

// ---------------- ext: bf16 rows + metric K-extension ----------------
// qext[row][144]: [bf16(x_k)]*128, dim128=1.0, dim129=1.0, rest 0
// cext[c][144]:   [bf16(-x_k)]*128, dim128=hb_hi, dim129=hb_lo, rest 0
// where hb = 0.5*rn[c] + 256  ->  mfma(C,Q) = 256 + hb - dot  (positive metric)
__global__ __launch_bounds__(256) void ext_kernel(const float* __restrict__ train,
                                                  const float* __restrict__ feat,
                                                  const float* __restrict__ rn,
                                                  u16* __restrict__ qext,
                                                  u16* __restrict__ cext) {
  int row = blockIdx.x * 2 + (threadIdx.x >> 7);  // 10240 blocks -> 20480
  int k = threadIdx.x & 127;
  const float* srcp = (row < NTR) ? (train + (size_t)row * DF) : (feat + (size_t)(row - NTR) * DF);
  float x = srcp[k];
  u16 b = bf16_rne(x);
  qext[(size_t)row * 144 + k] = b;
  if (row < NTR) cext[(size_t)row * 144 + k] = (u16)(b ^ 0x8000u);
  if (k < 16) {
    qext[(size_t)row * 144 + 128 + k] = (k < 2) ? (u16)0x3F80 : (u16)0;
    if (row < NTR) {
      float hbf = 0.5f * rn[row] + 256.0f;
      u16 hi = bf16_rne(hbf);
      u16 lo = bf16_rne(hbf - bf16_f32(hi));
      cext[(size_t)row * 144 + 128 + k] = (k == 0) ? hi : ((k == 1) ? lo : (u16)0);
    }
  }
}

// ---------------- FILTER: swapped 32x32x16 MFMA, 1 q-subtile/wave ------------
// Grid 2560: slice = bid&7 (XCD-affine), rowblk = bid>>3 (64 q rows/block).
// Selection v2: branch-free bitonic tile-merge on packed u32 keys (replaces
// per-candidate sorted insertion, which was 90% VALUBusy in r10). Identical
// top-16-by-key semantics -> fsn bit-identical.
__global__ __launch_bounds__(256, 3) void filter_kernel(const u16* __restrict__ qext,
                                                        const u16* __restrict__ cext,
                                                        u16* __restrict__ fsn) {
  __shared__ __align__(16) char smem[36864];  // cbuf[2]:16KB, hbuf[2]:2KB
  const int bid = blockIdx.x;
  const int slice = bid & 7, rowblk = bid >> 3;
  const int grow0 = rowblk * 64;
  const int cslice0 = slice * 2048;
  const int tid = threadIdx.x;
  const int wave = tid >> 6, lane = tid & 63;
  const int wq = wave >> 1, wc = wave & 1;
  const int l31 = lane & 31, h = lane >> 5;
  const char* qb = (const char*)qext;
  const char* cbg = (const char*)cext;

  // q fragments in registers: 9 ksteps for this wave's 32-row q-subtile
  bf16x8 qf[9];
  const int qrow = grow0 + wq * 32 + l31;
#pragma unroll
  for (int ks = 0; ks < 8; ++ks)
    qf[ks] = *(const bf16x8*)(qb + (size_t)qrow * 288 + ks * 32 + h * 16);
  qf[8] = *(const bf16x8*)(qb + (size_t)qrow * 288 + 256 + h * 16);

  u32 sd[16];
#pragma unroll
  for (int t = 0; t < 16; ++t) sd[t] = 0x7F7FFFFFu;

  // async stage of cand tile nt into buffer buf (source pre-swizzled, LDS linear)
  auto STAGE = [&](int buf, int nt) {
    const size_t c0 = (size_t)cslice0 + (size_t)nt * 64;
    char* cb = smem + buf * 16384;
    char* hb = smem + 32768 + buf * 2048;
#pragma unroll
    for (int j = 0; j < 4; ++j) {
      int I = wave + 4 * j;          // 0..15
      int G = I * 64 + lane;
      int r = G >> 4, g = G & 15;
      const char* src = cbg + (c0 + r) * 288 + ((g << 4) ^ ((r & 7) << 4));
      gload_lds16(src, cb + I * 1024);
    }
    if (wave < 2) {                  // 2 issues for hb dims (32B/row)
      int GG = wave * 64 + lane;
      int r = GG >> 1, half = GG & 1;
      const char* src = cbg + (c0 + r) * 288 + 256 + half * 16;
      gload_lds16(src, hb + wave * 1024);
    }
  };

  STAGE(0, 0);
  __syncthreads();

  const int crow = wc * 32 + l31;
  for (int nt = 0; nt < 32; ++nt) {
    const int cur = nt & 1;
    if (nt < 31) STAGE(cur ^ 1, nt + 1);

    const char* cbp = smem + cur * 16384 + crow * 256;
    const char* hbp = smem + 32768 + cur * 2048 + crow * 32 + h * 16;
    f32x16 acc = {0.f,0.f,0.f,0.f,0.f,0.f,0.f,0.f,0.f,0.f,0.f,0.f,0.f,0.f,0.f,0.f};
#pragma unroll
    for (int ks = 0; ks < 8; ++ks) {
      bf16x8 cf = *(const bf16x8*)(cbp + ((ks * 32 + h * 16) ^ ((crow & 7) << 4)));
      acc = __builtin_amdgcn_mfma_f32_32x32x16_bf16(cf, qf[ks], acc, 0, 0, 0);
    }
    {
      bf16x8 cf = *(const bf16x8*)hbp;
      acc = __builtin_amdgcn_mfma_f32_32x32x16_bf16(cf, qf[8], acc, 0, 0, 0);
    }

    // ---- selection v2: pack keys, guard, bitonic tile-merge (branch-free) ---
    const u32 cb_idx = (u32)(nt * 64 + wc * 32 + 4 * h);
    u32 tk[16];
#pragma unroll
    for (int j = 0; j < 16; ++j) {
      u32 off = (u32)((j & 3) + 8 * (j >> 2));
      tk[j] = (__float_as_uint(acc[j]) & 0xFFFFF000u) + cb_idx + off;  // low12 clear -> add==or
    }
    u32 tmin = tk[0];
#pragma unroll
    for (int j = 1; j < 16; ++j) tmin = tmin < tk[j] ? tmin : tk[j];
    if (tmin < sd[15]) {
      // bitonic sort tk ascending (all indices compile-time)
#pragma unroll
      for (int k = 2; k <= 16; k <<= 1)
#pragma unroll
        for (int j = k >> 1; j > 0; j >>= 1)
#pragma unroll
          for (int i = 0; i < 16; ++i) {
            int l = i ^ j;
            if (l > i) {
              bool asc = ((i & k) == 0);
              u32 a = tk[i], b = tk[l];
              u32 lo = a < b ? a : b, hi = a < b ? b : a;
              tk[i] = asc ? lo : hi;
              tk[l] = asc ? hi : lo;
            }
          }
      // merge: lowest 16 of (sd asc ++ reverse(tk)) is bitonic; then clean
      u32 m[16];
#pragma unroll
      for (int i = 0; i < 16; ++i) {
        u32 a = sd[i], b = tk[15 - i];
        m[i] = a < b ? a : b;
      }
#pragma unroll
      for (int j = 8; j > 0; j >>= 1)
#pragma unroll
        for (int i = 0; i < 16; ++i) {
          int l = i ^ j;
          if (l > i) {
            u32 a = m[i], b = m[l];
            m[i] = a < b ? a : b;
            m[l] = a < b ? b : a;
          }
        }
#pragma unroll
      for (int i = 0; i < 16; ++i) sd[i] = m[i];
    }
    __syncthreads();  // staged next buf ready; reads of cur complete
  }

  // dump per-thread lists, then 4-way merge per row -> fsn[row][slice*24..+24]
  u32* md = (u32*)smem;
  {
    int b = tid * 16;
#pragma unroll
    for (int t = 0; t < 16; ++t) md[b + t] = sd[t];
  }
  __syncthreads();
  if (tid < 64) {
    const int r = tid;                 // row within block (wq*32 + qcol)
    const int rwq = r >> 5, rl = r & 31;
    const u32* L[4];
#pragma unroll
    for (int wcc = 0; wcc < 2; ++wcc)
#pragma unroll
      for (int hh = 0; hh < 2; ++hh)
        L[wcc * 2 + hh] = md + (size_t)((rwq * 2 + wcc) * 64 + hh * 32 + rl) * 16;
    int p0 = 0, p1 = 0, p2 = 0, p3 = 0;
    size_t ob = (size_t)(grow0 + r) * 192 + (size_t)slice * 24;
    for (int t = 0; t < 24; ++t) {
      u32 k0 = (p0 < 16) ? L[0][p0] : 0xFFFFFFFFu;
      u32 k1 = (p1 < 16) ? L[1][p1] : 0xFFFFFFFFu;
      u32 k2 = (p2 < 16) ? L[2][p2] : 0xFFFFFFFFu;
      u32 k3 = (p3 < 16) ? L[3][p3] : 0xFFFFFFFFu;
      bool a01 = k0 <= k1; u32 kA = a01 ? k0 : k1;
      bool a23 = k2 <= k3; u32 kB = a23 ? k2 : k3;
      bool ab = kA <= kB;  u32 km = ab ? kA : kB;
      fsn[ob + t] = (u16)(cslice0 + (km & 0xFFFu));
      int win = ab ? (a01 ? 0 : 1) : (a23 ? 2 : 3);
      p0 += (win == 0); p1 += (win == 1); p2 += (win == 2); p3 += (win == 3);
    }
  }
}

// ---------------- RESCORE: exact no-FMA chain on 192 cands/row, rank-select --
// float4 candidate loads with one-chunk-ahead prefetch + float4 LDS query
// reads; the ascending-k add chain (data-dependent on s) is order-preserved,
// so scores are bit-identical to the verified realization.
__global__ __launch_bounds__(192) void rescore_kernel(const float* __restrict__ train,
                                                      const float* __restrict__ feat,
                                                      const float* __restrict__ rn,
                                                      const u16* __restrict__ fsn,
                                                      int* __restrict__ nbrt,
                                                      int* __restrict__ nbrq) {
  __shared__ __align__(16) float rowf[DF];
  __shared__ __align__(16) float sc[192];
  __shared__ __align__(16) int sidx[192];
  const int row = blockIdx.x;  // 20480 blocks
  const int t = threadIdx.x;
  const float* src = (row < NTR) ? (train + (size_t)row * DF) : (feat + (size_t)(row - NTR) * DF);
  if (t < DF) rowf[t] = src[t];
  __syncthreads();
  {
    int ci = (int)fsn[(size_t)row * 192 + t];
    if (ci >= NTR) ci = NTR - 1;  // defensive (bug -> absmax, not fault)
    const float* tv = train + (size_t)ci * DF;
    float4 b0 = *(const float4*)(tv + 0);
    float4 b1 = *(const float4*)(tv + 4);
    float4 b2 = *(const float4*)(tv + 8);
    float4 b3 = *(const float4*)(tv + 12);
    float s = 0.0f;
#pragma unroll
    for (int ch = 0; ch < 8; ++ch) {
      float4 n0, n1, n2, n3;
      if (ch < 7) {
        const float* nx = tv + (ch + 1) * 16;
        n0 = *(const float4*)(nx + 0);
        n1 = *(const float4*)(nx + 4);
        n2 = *(const float4*)(nx + 8);
        n3 = *(const float4*)(nx + 12);
      }
      float4 q0 = *(const float4*)&rowf[ch * 16 + 0];
      float4 q1 = *(const float4*)&rowf[ch * 16 + 4];
      float4 q2 = *(const float4*)&rowf[ch * 16 + 8];
      float4 q3 = *(const float4*)&rowf[ch * 16 + 12];
      // strict ascending-k chain (order fixed by the dependence on s)
      s = s + mulr(q0.x, b0.x); s = s + mulr(q0.y, b0.y);
      s = s + mulr(q0.z, b0.z); s = s + mulr(q0.w, b0.w);
      s = s + mulr(q1.x, b1.x); s = s + mulr(q1.y, b1.y);
      s = s + mulr(q1.z, b1.z); s = s + mulr(q1.w, b1.w);
      s = s + mulr(q2.x, b2.x); s = s + mulr(q2.y, b2.y);
      s = s + mulr(q2.z, b2.z); s = s + mulr(q2.w, b2.w);
      s = s + mulr(q3.x, b3.x); s = s + mulr(q3.y, b3.y);
      s = s + mulr(q3.z, b3.z); s = s + mulr(q3.w, b3.w);
      if (ch < 7) { b0 = n0; b1 = n1; b2 = n2; b3 = n3; }
    }
    float t1 = rn[row] + rn[ci];
    sc[t] = t1 - 2.0f * s;
    sidx[t] = ci;
  }
  __syncthreads();
  {
    float dm = sc[t];
    int im = sidx[t];
    int rank = 0;
#pragma unroll 4
    for (int i = 0; i < 192; i += 4) {
      float4 d4 = *(const float4*)&sc[i];
      int4 i4 = *(const int4*)&sidx[i];
      rank += (d4.x < dm || (d4.x == dm && i4.x < im));
      rank += (d4.y < dm || (d4.y == dm && i4.y < im));
      rank += (d4.z < dm || (d4.z == dm && i4.z < im));
      rank += (d4.w < dm || (d4.w == dm && i4.w < im));
    }
    if (rank < 20) {
      int* outp = (row < NTR) ? (nbrt + (size_t)row * 20) : (nbrq + (size_t)(row - NTR) * 20);
      outp[rank] = im;
    }
  }
}

// ---------------- label-count histograms (k=10 and k=20) ----------------
__global__ __launch_bounds__(256) void hist_kernel(const int* __restrict__ labels,
                                                   const int* __restrict__ nbrt,
                                                   int* __restrict__ ghist) {
  __shared__ int h[2432];
  int tid = threadIdx.x;
  for (int i = tid; i < 2432; i += 256) h[i] = 0;
  __syncthreads();
  int row = blockIdx.x * 256 + tid;  // 64 blocks -> 16384
  int nb[20];
#pragma unroll
  for (int j = 0; j < 20; ++j) nb[j] = nbrt[(size_t)row * 20 + j];
  int cnt[NCL];
#pragma unroll
  for (int c = 0; c < NCL; ++c) cnt[c] = 0;
#pragma unroll
  for (int j = 0; j < 10; ++j) {
    const int* lr = labels + (size_t)nb[j] * NCL;
#pragma unroll
    for (int c = 0; c < NCL; ++c) cnt[c] += lr[c];
  }
  const int* myl = labels + (size_t)row * NCL;
  int my[NCL];
#pragma unroll
  for (int c = 0; c < NCL; ++c) my[c] = myl[c];
#pragma unroll
  for (int c = 0; c < NCL; ++c)
    atomicAdd(&h[((0 * 2 + my[c]) * NCL + c) * 32 + cnt[c]], 1);
#pragma unroll
  for (int j = 10; j < 20; ++j) {
    const int* lr = labels + (size_t)nb[j] * NCL;
#pragma unroll
    for (int c = 0; c < NCL; ++c) cnt[c] += lr[c];
  }
#pragma unroll
  for (int c = 0; c < NCL; ++c)
    atomicAdd(&h[((1 * 2 + my[c]) * NCL + c) * 32 + cnt[c]], 1);
  __syncthreads();
  for (int i = tid; i < 2432; i += 256) {
    int v = h[i];
    if (v) atomicAdd(&ghist[i], v);
  }
}

// ---------------- conditional tables + priors ----------------
__global__ __launch_bounds__(256) void prep_kernel(const int* __restrict__ ghist,
                                                   float* __restrict__ cond,
                                                   float* __restrict__ prior) {
  __shared__ int cpos[NCL];
  int tid = threadIdx.x;
  if (tid < NCL) {
    int s = 0;
    for (int d = 0; d < 32; ++d) s += ghist[((0 * 2 + 1) * NCL + tid) * 32 + d];
    cpos[tid] = s;
    prior[tid] = (1.0f + (float)s) / (2.0f + (float)NTR);
  }
  __syncthreads();
  for (int i = tid; i < 2432; i += 256) {
    int cc = (i >> 5) % NCL;
    int pos = ((i >> 5) / NCL) & 1;
    int ki = i / (2 * NCL * 32);
    int k = ki ? 20 : 10;
    float num = 1.0f + (float)ghist[i];
    float den = (float)(k + 1) + (float)(pos ? cpos[cc] : (NTR - cpos[cc]));
    cond[i] = num / den;
  }
}

// ---------------- posterior output ----------------
__global__ __launch_bounds__(256) void out_kernel(const int* __restrict__ labels,
                                                  const int* __restrict__ nbrq,
                                                  const float* __restrict__ cond,
                                                  const float* __restrict__ prior,
                                                  float* __restrict__ out) {
  int q = blockIdx.x * 256 + threadIdx.x;  // 16 blocks -> 4096
  int nb[20];
#pragma unroll
  for (int j = 0; j < 20; ++j) nb[j] = nbrq[(size_t)q * 20 + j];
  int cnt[NCL], d10[NCL];
#pragma unroll
  for (int c = 0; c < NCL; ++c) cnt[c] = 0;
#pragma unroll
  for (int j = 0; j < 10; ++j) {
    const int* lr = labels + (size_t)nb[j] * NCL;
#pragma unroll
    for (int c = 0; c < NCL; ++c) cnt[c] += lr[c];
  }
#pragma unroll
  for (int c = 0; c < NCL; ++c) d10[c] = cnt[c];
#pragma unroll
  for (int j = 10; j < 20; ++j) {
    const int* lr = labels + (size_t)nb[j] * NCL;
#pragma unroll
    for (int c = 0; c < NCL; ++c) cnt[c] += lr[c];
  }
#pragma unroll
  for (int ki = 0; ki < 2; ++ki) {
#pragma unroll
    for (int c = 0; c < NCL; ++c) {
      int delta = ki ? cnt[c] : d10[c];
      float pr = prior[c];
      float pt = pr * cond[((ki * 2 + 1) * NCL + c) * 32 + delta];
      float pf = (1.0f - pr) * cond[((ki * 2 + 0) * NCL + c) * 32 + delta];
      out[((size_t)ki * NQR + q) * NCL + c] = pt / (pt + pf);
    }
  }
}

extern "C" void kernel_launch(void* const* d_in, const int* in_sizes, int n_in,
                              void* d_out, int out_size, void* d_ws, size_t ws_size,
                              hipStream_t stream) {
  const float* feat = (const float*)d_in[0];     // [4096,128]
  const float* train = (const float*)d_in[1];    // [16384,128]
  const int* labels = (const int*)d_in[2];       // [16384,19]
  float* out = (float*)d_out;                    // [2,4096,19]
  if (ws_size < WS_NEEDED) return;               // loud failure via poisoned output
  char* w = (char*)d_ws;
  float* rn = (float*)(w + OFF_RN);
  u16* qext = (u16*)(w + OFF_QEXT);
  u16* cext = (u16*)(w + OFF_CEXT);
  u16* fsn = (u16*)(w + OFF_FSN);
  int* nbrt = (int*)(w + OFF_NBRT);
  int* nbrq = (int*)(w + OFF_NBRQ);
  int* ghist = (int*)(w + OFF_HIST);
  float* cond = (float*)(w + OFF_COND);
  float* prior = (float*)(w + OFF_PRIOR);

  hipMemsetAsync(ghist, 0, 2432 * 4, stream);
  norms_kernel<<<80, 256, 0, stream>>>(train, feat, rn);
  ext_kernel<<<10240, 256, 0, stream>>>(train, feat, rn, qext, cext);
  filter_kernel<<<2560, 256, 0, stream>>>(qext, cext, fsn);
  rescore_kernel<<<20480, 192, 0, stream>>>(train, feat, rn, fsn, nbrt, nbrq);
  hist_kernel<<<64, 256, 0, stream>>>(labels, nbrt, ghist);
  prep_kernel<<<1, 256, 0, stream>>>(ghist, cond, prior);
  out_kernel<<<16, 256, 0, stream>>>(labels, nbrq, cond, prior, out);
}

// Round 12
// 415.962 us; speedup vs baseline: 9.7542x; 1.2902x over previous
//
#include <hip/hip_runtime.h>
#include <cstdint>
#include <cstddef>

#define NTR 16384
#define NQR 4096
#define NROW 20480
#define DF  128
#define NCL 19

typedef unsigned short u16;
typedef unsigned int u32;
typedef __attribute__((ext_vector_type(8))) short bf16x8;
typedef __attribute__((ext_vector_type(16))) float f32x16;

// ---- workspace layout (bytes) ----
#define OFF_RN    (size_t)0                  // float[20480]
#define OFF_QEXT  (size_t)81920              // u16[20480][144]
#define OFF_CEXT  (size_t)5980160            // u16[16384][144] (negated + hb dims)
#define OFF_FSN   (size_t)10698752           // u16[20480][96]
#define OFF_NBRT  (size_t)18563072           // int[16384][20]
#define OFF_NBRQ  (size_t)19873792           // int[4096][20]
#define OFF_HIST  (size_t)20201472           // int[2][2][19][32]
#define OFF_COND  (size_t)20211200           // float[2][2][19][32]
#define OFF_PRIOR (size_t)20220928           // float[19]
#define WS_NEEDED (size_t)20221008

// separately-rounded multiply (asm barrier blocks mul+add -> fma contraction)
__device__ __forceinline__ float mulr(float a, float b) {
  float m = a * b;
  asm volatile("" : "+v"(m));
  return m;
}

__device__ __forceinline__ u16 bf16_rne(float x) {
  union { float f; unsigned u; } v; v.f = x;
  unsigned r = (v.u + 0x7fffu + ((v.u >> 16) & 1u)) >> 16;
  return (u16)r;
}
__device__ __forceinline__ float bf16_f32(u16 h) {
  union { unsigned u; float f; } v; v.u = ((unsigned)h) << 16;
  return v.f;
}

__device__ __forceinline__ void gload_lds16(const void* g, void* lds) {
  __builtin_amdgcn_global_load_lds(
      (const __attribute__((address_space(1))) unsigned int*)g,
      (__attribute__((address_space(3))) unsigned int*)lds, 16, 0, 0);
}

// ---------------- row norms: exact reference realization (no FMA) ------------
__global__ __launch_bounds__(256) void norms_kernel(const float* __restrict__ train,
                                                    const float* __restrict__ feat,
                                                    float* __restrict__ rn) {
  int i = blockIdx.x * 256 + threadIdx.x;  // 80 blocks -> 20480
  const float* src = (i < NTR) ? (train + (size_t)i * DF) : (feat + (size_t)(i - NTR) * DF);
  float s = 0.0f;
  for (int k = 0; k < DF; ++k) {
    float x = src[k];
    s = s + mulr(x, x);
  }
  rn[i] = s;
}

// ---------------- ext: bf16 rows + metric K-extension ----------------
// qext[row][144]: [bf16(x_k)]*128, dim128=1.0, dim129=1.0, rest 0
// cext[c][144]:   [bf16(-x_k)]*128, dim128=hb_hi, dim129=hb_lo, rest 0
// where hb = 0.5*rn[c] + 256  ->  mfma(C,Q) = 256 + hb - dot  (positive metric)
__global__ __launch_bounds__(256) void ext_kernel(const float* __restrict__ train,
                                                  const float* __restrict__ feat,
                                                  const float* __restrict__ rn,
                                                  u16* __restrict__ qext,
                                                  u16* __restrict__ cext) {
  int row = blockIdx.x * 2 + (threadIdx.x >> 7);  // 10240 blocks -> 20480
  int k = threadIdx.x & 127;
  const float* srcp = (row < NTR) ? (train + (size_t)row * DF) : (feat + (size_t)(row - NTR) * DF);
  float x = srcp[k];
  u16 b = bf16_rne(x);
  qext[(size_t)row * 144 + k] = b;
  if (row < NTR) cext[(size_t)row * 144 + k] = (u16)(b ^ 0x8000u);
  if (k < 16) {
    qext[(size_t)row * 144 + 128 + k] = (k < 2) ? (u16)0x3F80 : (u16)0;
    if (row < NTR) {
      float hbf = 0.5f * rn[row] + 256.0f;
      u16 hi = bf16_rne(hbf);
      u16 lo = bf16_rne(hbf - bf16_f32(hi));
      cext[(size_t)row * 144 + 128 + k] = (k == 0) ? hi : ((k == 1) ? lo : (u16)0);
    }
  }
}

// ---------------- FILTER: swapped 32x32x16 MFMA, 1 q-subtile/wave ------------
// Grid 1280: slice = bid&3 (each XCD sees exactly one 1.18MB cand slice in L2
// under round-robin dispatch), rowblk = bid>>2 (64 q rows/block).
// 64 n-tiles of 64 cands. Selection: branch-free bitonic tile-merge on packed
// u32 keys (20 float bits | 12-bit slice-local idx, metric > 0).
__global__ __launch_bounds__(256, 3) void filter_kernel(const u16* __restrict__ qext,
                                                        const u16* __restrict__ cext,
                                                        u16* __restrict__ fsn) {
  __shared__ __align__(16) char smem[36864];  // cbuf[2]:16KB, hbuf[2]:2KB
  const int bid = blockIdx.x;
  const int slice = bid & 3, rowblk = bid >> 2;
  const int grow0 = rowblk * 64;
  const int cslice0 = slice * 4096;
  const int tid = threadIdx.x;
  const int wave = tid >> 6, lane = tid & 63;
  const int wq = wave >> 1, wc = wave & 1;
  const int l31 = lane & 31, h = lane >> 5;
  const char* qb = (const char*)qext;
  const char* cbg = (const char*)cext;

  // q fragments in registers: 9 ksteps for this wave's 32-row q-subtile
  bf16x8 qf[9];
  const int qrow = grow0 + wq * 32 + l31;
#pragma unroll
  for (int ks = 0; ks < 8; ++ks)
    qf[ks] = *(const bf16x8*)(qb + (size_t)qrow * 288 + ks * 32 + h * 16);
  qf[8] = *(const bf16x8*)(qb + (size_t)qrow * 288 + 256 + h * 16);

  u32 sd[16];
#pragma unroll
  for (int t = 0; t < 16; ++t) sd[t] = 0x7F7FFFFFu;

  // async stage of cand tile nt into buffer buf (source pre-swizzled, LDS linear)
  auto STAGE = [&](int buf, int nt) {
    const size_t c0 = (size_t)cslice0 + (size_t)nt * 64;
    char* cb = smem + buf * 16384;
    char* hb = smem + 32768 + buf * 2048;
#pragma unroll
    for (int j = 0; j < 4; ++j) {
      int I = wave + 4 * j;          // 0..15
      int G = I * 64 + lane;
      int r = G >> 4, g = G & 15;
      const char* src = cbg + (c0 + r) * 288 + ((g << 4) ^ ((r & 7) << 4));
      gload_lds16(src, cb + I * 1024);
    }
    if (wave < 2) {                  // 2 issues for hb dims (32B/row)
      int GG = wave * 64 + lane;
      int r = GG >> 1, half = GG & 1;
      const char* src = cbg + (c0 + r) * 288 + 256 + half * 16;
      gload_lds16(src, hb + wave * 1024);
    }
  };

  STAGE(0, 0);
  __syncthreads();

  const int crow = wc * 32 + l31;
  for (int nt = 0; nt < 64; ++nt) {
    const int cur = nt & 1;
    if (nt < 63) STAGE(cur ^ 1, nt + 1);

    const char* cbp = smem + cur * 16384 + crow * 256;
    const char* hbp = smem + 32768 + cur * 2048 + crow * 32 + h * 16;
    f32x16 acc = {0.f,0.f,0.f,0.f,0.f,0.f,0.f,0.f,0.f,0.f,0.f,0.f,0.f,0.f,0.f,0.f};
#pragma unroll
    for (int ks = 0; ks < 8; ++ks) {
      bf16x8 cf = *(const bf16x8*)(cbp + ((ks * 32 + h * 16) ^ ((crow & 7) << 4)));
      acc = __builtin_amdgcn_mfma_f32_32x32x16_bf16(cf, qf[ks], acc, 0, 0, 0);
    }
    {
      bf16x8 cf = *(const bf16x8*)hbp;
      acc = __builtin_amdgcn_mfma_f32_32x32x16_bf16(cf, qf[8], acc, 0, 0, 0);
    }

    // ---- selection: pack keys, guard, bitonic tile-merge (branch-free) ----
    const u32 cb_idx = (u32)(nt * 64 + wc * 32 + 4 * h);
    u32 tk[16];
#pragma unroll
    for (int j = 0; j < 16; ++j) {
      u32 off = (u32)((j & 3) + 8 * (j >> 2));
      tk[j] = (__float_as_uint(acc[j]) & 0xFFFFF000u) + cb_idx + off;  // low12 clear -> add==or
    }
    u32 tmin = tk[0];
#pragma unroll
    for (int j = 1; j < 16; ++j) tmin = tmin < tk[j] ? tmin : tk[j];
    if (tmin < sd[15]) {
      // bitonic sort tk ascending (all indices compile-time)
#pragma unroll
      for (int k = 2; k <= 16; k <<= 1)
#pragma unroll
        for (int j = k >> 1; j > 0; j >>= 1)
#pragma unroll
          for (int i = 0; i < 16; ++i) {
            int l = i ^ j;
            if (l > i) {
              bool asc = ((i & k) == 0);
              u32 a = tk[i], b = tk[l];
              u32 lo = a < b ? a : b, hi = a < b ? b : a;
              tk[i] = asc ? lo : hi;
              tk[l] = asc ? hi : lo;
            }
          }
      // merge: lowest 16 of (sd asc ++ reverse(tk)) is bitonic; then clean
      u32 m[16];
#pragma unroll
      for (int i = 0; i < 16; ++i) {
        u32 a = sd[i], b = tk[15 - i];
        m[i] = a < b ? a : b;
      }
#pragma unroll
      for (int j = 8; j > 0; j >>= 1)
#pragma unroll
        for (int i = 0; i < 16; ++i) {
          int l = i ^ j;
          if (l > i) {
            u32 a = m[i], b = m[l];
            m[i] = a < b ? a : b;
            m[l] = a < b ? b : a;
          }
        }
#pragma unroll
      for (int i = 0; i < 16; ++i) sd[i] = m[i];
    }
    __syncthreads();  // staged next buf ready; reads of cur complete
  }

  // dump per-thread lists, then 4-way merge per row -> fsn[row][slice*24..+24]
  u32* md = (u32*)smem;
  {
    int b = tid * 16;
#pragma unroll
    for (int t = 0; t < 16; ++t) md[b + t] = sd[t];
  }
  __syncthreads();
  if (tid < 64) {
    const int r = tid;                 // row within block (wq*32 + qcol)
    const int rwq = r >> 5, rl = r & 31;
    const u32* L[4];
#pragma unroll
    for (int wcc = 0; wcc < 2; ++wcc)
#pragma unroll
      for (int hh = 0; hh < 2; ++hh)
        L[wcc * 2 + hh] = md + (size_t)((rwq * 2 + wcc) * 64 + hh * 32 + rl) * 16;
    int p0 = 0, p1 = 0, p2 = 0, p3 = 0;
    size_t ob = (size_t)(grow0 + r) * 96 + (size_t)slice * 24;
    for (int t = 0; t < 24; ++t) {
      u32 k0 = (p0 < 16) ? L[0][p0] : 0xFFFFFFFFu;
      u32 k1 = (p1 < 16) ? L[1][p1] : 0xFFFFFFFFu;
      u32 k2 = (p2 < 16) ? L[2][p2] : 0xFFFFFFFFu;
      u32 k3 = (p3 < 16) ? L[3][p3] : 0xFFFFFFFFu;
      bool a01 = k0 <= k1; u32 kA = a01 ? k0 : k1;
      bool a23 = k2 <= k3; u32 kB = a23 ? k2 : k3;
      bool ab = kA <= kB;  u32 km = ab ? kA : kB;
      fsn[ob + t] = (u16)(cslice0 + (km & 0xFFFu));
      int win = ab ? (a01 ? 0 : 1) : (a23 ? 2 : 3);
      p0 += (win == 0); p1 += (win == 1); p2 += (win == 2); p3 += (win == 3);
    }
  }
}

// ---------------- RESCORE: exact no-FMA chain on 96 cands/row, rank-select ---
// 2 rows/block x 96 threads. float4 candidate loads with one-chunk-ahead
// prefetch; the ascending-k add chain (data-dependent on s) is order-preserved,
// so scores are bit-identical to the verified realization.
__global__ __launch_bounds__(192) void rescore_kernel(const float* __restrict__ train,
                                                      const float* __restrict__ feat,
                                                      const float* __restrict__ rn,
                                                      const u16* __restrict__ fsn,
                                                      int* __restrict__ nbrt,
                                                      int* __restrict__ nbrq) {
  __shared__ __align__(16) float rowf[2][DF];
  __shared__ __align__(16) float sc[2][96];
  __shared__ __align__(16) int sidx[2][96];
  const int tid = threadIdx.x;
  const int sub = (tid >= 96) ? 1 : 0;
  const int t = tid - sub * 96;
  const int row = blockIdx.x * 2 + sub;  // 10240 blocks -> 20480
  const float* src = (row < NTR) ? (train + (size_t)row * DF) : (feat + (size_t)(row - NTR) * DF);
  for (int i = t; i < DF; i += 96) rowf[sub][i] = src[i];
  __syncthreads();
  {
    int ci = (int)fsn[(size_t)row * 96 + t];
    if (ci >= NTR) ci = NTR - 1;  // defensive (bug -> absmax, not fault)
    const float* tv = train + (size_t)ci * DF;
    float4 b0 = *(const float4*)(tv + 0);
    float4 b1 = *(const float4*)(tv + 4);
    float4 b2 = *(const float4*)(tv + 8);
    float4 b3 = *(const float4*)(tv + 12);
    float s = 0.0f;
#pragma unroll
    for (int ch = 0; ch < 8; ++ch) {
      float4 n0, n1, n2, n3;
      if (ch < 7) {
        const float* nx = tv + (ch + 1) * 16;
        n0 = *(const float4*)(nx + 0);
        n1 = *(const float4*)(nx + 4);
        n2 = *(const float4*)(nx + 8);
        n3 = *(const float4*)(nx + 12);
      }
      float4 q0 = *(const float4*)&rowf[sub][ch * 16 + 0];
      float4 q1 = *(const float4*)&rowf[sub][ch * 16 + 4];
      float4 q2 = *(const float4*)&rowf[sub][ch * 16 + 8];
      float4 q3 = *(const float4*)&rowf[sub][ch * 16 + 12];
      // strict ascending-k chain (order fixed by the dependence on s)
      s = s + mulr(q0.x, b0.x); s = s + mulr(q0.y, b0.y);
      s = s + mulr(q0.z, b0.z); s = s + mulr(q0.w, b0.w);
      s = s + mulr(q1.x, b1.x); s = s + mulr(q1.y, b1.y);
      s = s + mulr(q1.z, b1.z); s = s + mulr(q1.w, b1.w);
      s = s + mulr(q2.x, b2.x); s = s + mulr(q2.y, b2.y);
      s = s + mulr(q2.z, b2.z); s = s + mulr(q2.w, b2.w);
      s = s + mulr(q3.x, b3.x); s = s + mulr(q3.y, b3.y);
      s = s + mulr(q3.z, b3.z); s = s + mulr(q3.w, b3.w);
      if (ch < 7) { b0 = n0; b1 = n1; b2 = n2; b3 = n3; }
    }
    float t1 = rn[row] + rn[ci];
    sc[sub][t] = t1 - 2.0f * s;
    sidx[sub][t] = ci;
  }
  __syncthreads();
  {
    float dm = sc[sub][t];
    int im = sidx[sub][t];
    int rank = 0;
#pragma unroll 4
    for (int i = 0; i < 96; i += 4) {
      float4 d4 = *(const float4*)&sc[sub][i];
      int4 i4 = *(const int4*)&sidx[sub][i];
      rank += (d4.x < dm || (d4.x == dm && i4.x < im));
      rank += (d4.y < dm || (d4.y == dm && i4.y < im));
      rank += (d4.z < dm || (d4.z == dm && i4.z < im));
      rank += (d4.w < dm || (d4.w == dm && i4.w < im));
    }
    if (rank < 20) {
      int* outp = (row < NTR) ? (nbrt + (size_t)row * 20) : (nbrq + (size_t)(row - NTR) * 20);
      outp[rank] = im;
    }
  }
}

// ---------------- label-count histograms (k=10 and k=20) ----------------
__global__ __launch_bounds__(256) void hist_kernel(const int* __restrict__ labels,
                                                   const int* __restrict__ nbrt,
                                                   int* __restrict__ ghist) {
  __shared__ int h[2432];
  int tid = threadIdx.x;
  for (int i = tid; i < 2432; i += 256) h[i] = 0;
  __syncthreads();
  int row = blockIdx.x * 256 + tid;  // 64 blocks -> 16384
  int nb[20];
#pragma unroll
  for (int j = 0; j < 20; ++j) nb[j] = nbrt[(size_t)row * 20 + j];
  int cnt[NCL];
#pragma unroll
  for (int c = 0; c < NCL; ++c) cnt[c] = 0;
#pragma unroll
  for (int j = 0; j < 10; ++j) {
    const int* lr = labels + (size_t)nb[j] * NCL;
#pragma unroll
    for (int c = 0; c < NCL; ++c) cnt[c] += lr[c];
  }
  const int* myl = labels + (size_t)row * NCL;
  int my[NCL];
#pragma unroll
  for (int c = 0; c < NCL; ++c) my[c] = myl[c];
#pragma unroll
  for (int c = 0; c < NCL; ++c)
    atomicAdd(&h[((0 * 2 + my[c]) * NCL + c) * 32 + cnt[c]], 1);
#pragma unroll
  for (int j = 10; j < 20; ++j) {
    const int* lr = labels + (size_t)nb[j] * NCL;
#pragma unroll
    for (int c = 0; c < NCL; ++c) cnt[c] += lr[c];
  }
#pragma unroll
  for (int c = 0; c < NCL; ++c)
    atomicAdd(&h[((1 * 2 + my[c]) * NCL + c) * 32 + cnt[c]], 1);
  __syncthreads();
  for (int i = tid; i < 2432; i += 256) {
    int v = h[i];
    if (v) atomicAdd(&ghist[i], v);
  }
}

// ---------------- conditional tables + priors ----------------
__global__ __launch_bounds__(256) void prep_kernel(const int* __restrict__ ghist,
                                                   float* __restrict__ cond,
                                                   float* __restrict__ prior) {
  __shared__ int cpos[NCL];
  int tid = threadIdx.x;
  if (tid < NCL) {
    int s = 0;
    for (int d = 0; d < 32; ++d) s += ghist[((0 * 2 + 1) * NCL + tid) * 32 + d];
    cpos[tid] = s;
    prior[tid] = (1.0f + (float)s) / (2.0f + (float)NTR);
  }
  __syncthreads();
  for (int i = tid; i < 2432; i += 256) {
    int cc = (i >> 5) % NCL;
    int pos = ((i >> 5) / NCL) & 1;
    int ki = i / (2 * NCL * 32);
    int k = ki ? 20 : 10;
    float num = 1.0f + (float)ghist[i];
    float den = (float)(k + 1) + (float)(pos ? cpos[cc] : (NTR - cpos[cc]));
    cond[i] = num / den;
  }
}

// ---------------- posterior output ----------------
__global__ __launch_bounds__(256) void out_kernel(const int* __restrict__ labels,
                                                  const int* __restrict__ nbrq,
                                                  const float* __restrict__ cond,
                                                  const float* __restrict__ prior,
                                                  float* __restrict__ out) {
  int q = blockIdx.x * 256 + threadIdx.x;  // 16 blocks -> 4096
  int nb[20];
#pragma unroll
  for (int j = 0; j < 20; ++j) nb[j] = nbrq[(size_t)q * 20 + j];
  int cnt[NCL], d10[NCL];
#pragma unroll
  for (int c = 0; c < NCL; ++c) cnt[c] = 0;
#pragma unroll
  for (int j = 0; j < 10; ++j) {
    const int* lr = labels + (size_t)nb[j] * NCL;
#pragma unroll
    for (int c = 0; c < NCL; ++c) cnt[c] += lr[c];
  }
#pragma unroll
  for (int c = 0; c < NCL; ++c) d10[c] = cnt[c];
#pragma unroll
  for (int j = 10; j < 20; ++j) {
    const int* lr = labels + (size_t)nb[j] * NCL;
#pragma unroll
    for (int c = 0; c < NCL; ++c) cnt[c] += lr[c];
  }
#pragma unroll
  for (int ki = 0; ki < 2; ++ki) {
#pragma unroll
    for (int c = 0; c < NCL; ++c) {
      int delta = ki ? cnt[c] : d10[c];
      float pr = prior[c];
      float pt = pr * cond[((ki * 2 + 1) * NCL + c) * 32 + delta];
      float pf = (1.0f - pr) * cond[((ki * 2 + 0) * NCL + c) * 32 + delta];
      out[((size_t)ki * NQR + q) * NCL + c] = pt / (pt + pf);
    }
  }
}

extern "C" void kernel_launch(void* const* d_in, const int* in_sizes, int n_in,
                              void* d_out, int out_size, void* d_ws, size_t ws_size,
                              hipStream_t stream) {
  const float* feat = (const float*)d_in[0];     // [4096,128]
  const float* train = (const float*)d_in[1];    // [16384,128]
  const int* labels = (const int*)d_in[2];       // [16384,19]
  float* out = (float*)d_out;                    // [2,4096,19]
  if (ws_size < WS_NEEDED) return;               // loud failure via poisoned output
  char* w = (char*)d_ws;
  float* rn = (float*)(w + OFF_RN);
  u16* qext = (u16*)(w + OFF_QEXT);
  u16* cext = (u16*)(w + OFF_CEXT);
  u16* fsn = (u16*)(w + OFF_FSN);
  int* nbrt = (int*)(w + OFF_NBRT);
  int* nbrq = (int*)(w + OFF_NBRQ);
  int* ghist = (int*)(w + OFF_HIST);
  float* cond = (float*)(w + OFF_COND);
  float* prior = (float*)(w + OFF_PRIOR);

  hipMemsetAsync(ghist, 0, 2432 * 4, stream);
  norms_kernel<<<80, 256, 0, stream>>>(train, feat, rn);
  ext_kernel<<<10240, 256, 0, stream>>>(train, feat, rn, qext, cext);
  filter_kernel<<<1280, 256, 0, stream>>>(qext, cext, fsn);
  rescore_kernel<<<10240, 192, 0, stream>>>(train, feat, rn, fsn, nbrt, nbrq);
  hist_kernel<<<64, 256, 0, stream>>>(labels, nbrt, ghist);
  prep_kernel<<<1, 256, 0, stream>>>(ghist, cond, prior);
  out_kernel<<<16, 256, 0, stream>>>(labels, nbrq, cond, prior, out);
}